// Round 14
// baseline (322.704 us; speedup 1.0000x reference)
//
#include <hip/hip_runtime.h>
#include <hip/hip_bf16.h>

#define NGR 10000
typedef unsigned int u32;
typedef __attribute__((ext_vector_type(8))) short short8;
typedef __attribute__((ext_vector_type(4))) float f32x4;

// ---------- threefry2x32 (JAX-exact) ----------
__device__ __forceinline__ void threefry(u32 k0, u32 k1, u32 c0, u32 c1, u32& o0, u32& o1) {
    u32 ks2 = k0 ^ k1 ^ 0x1BD11BDAu;
    u32 x0 = c0 + k0, x1 = c1 + k1;
#define TF_R(r) { x0 += x1; x1 = (x1 << r) | (x1 >> (32 - r)); x1 ^= x0; }
    TF_R(13) TF_R(15) TF_R(26) TF_R(6)
    x0 += k1; x1 += ks2 + 1u;
    TF_R(17) TF_R(29) TF_R(16) TF_R(24)
    x0 += ks2; x1 += k0 + 2u;
    TF_R(13) TF_R(15) TF_R(26) TF_R(6)
    x0 += k0; x1 += k1 + 3u;
    TF_R(17) TF_R(29) TF_R(16) TF_R(24)
    x0 += k1; x1 += ks2 + 4u;
    TF_R(13) TF_R(15) TF_R(26) TF_R(6)
    x0 += ks2; x1 += k0 + 5u;
#undef TF_R
    o0 = x0; o1 = x1;
}

// ---------- CSR build ----------
__global__ void k_deg(const int* __restrict__ dst, int* __restrict__ deg, int E) {
    int i = blockIdx.x * blockDim.x + threadIdx.x;
    if (i < E) atomicAdd(&deg[dst[i]], 1);
}
__global__ void k_scan(const int* __restrict__ deg, int* __restrict__ rowptr, int n) {
    __shared__ int sums[256];
    __shared__ int excl[257];
    const int T = 256;
    int t = threadIdx.x;
    int per = (n + T - 1) / T;
    int lo = t * per, hi = min(lo + per, n);
    int s = 0;
    for (int i = lo; i < hi; ++i) s += deg[i];
    sums[t] = s;
    __syncthreads();
    if (t == 0) { int run = 0; for (int i = 0; i < T; ++i) { excl[i] = run; run += sums[i]; } excl[T] = run; }
    __syncthreads();
    int run = excl[t];
    for (int i = lo; i < hi; ++i) { rowptr[i] = run; run += deg[i]; }
    if (t == 0) rowptr[n] = excl[T];
}
__global__ void k_scatter(const int* __restrict__ dst, const int* __restrict__ rowptr,
                          int* __restrict__ cursor, int* __restrict__ colidx, int E) {
    int i = blockIdx.x * blockDim.x + threadIdx.x;
    if (i >= E) return;
    int d = dst[i];
    int pos = atomicAdd(&cursor[d], 1);
    colidx[rowptr[d] + pos] = i;
}

// ---------- mega-prep ----------
#define TINYF 1.17549435e-38f
__global__ __launch_bounds__(256) void k_prep(
    const float* __restrict__ feat, const int* __restrict__ tptr,
    const float* __restrict__ Wt, const float* __restrict__ bt,
    const float* __restrict__ W1a, const float* __restrict__ W1e,
    const float* __restrict__ R1a, const float* __restrict__ R1e,
    const float* __restrict__ b1a, const float* __restrict__ b1e,
    const float* __restrict__ W2a, const float* __restrict__ al2a, const float* __restrict__ ar2a,
    unsigned short* __restrict__ feathi, unsigned short* __restrict__ featlo,
    unsigned short* __restrict__ WThi, unsigned short* __restrict__ WTlo,
    float* __restrict__ tf, float* __restrict__ gum, float* __restrict__ wal,
    float* __restrict__ packb, float* __restrict__ zreg)
{
    __shared__ float sh[32 * 33];
    int b = blockIdx.x, tid = threadIdx.x;
    if (b < 2500) {
        int idx = b * 256 + tid;
        float4 v = ((const float4*)feat)[idx];
        ushort4 h, l;
        __hip_bfloat16 bb; float r;
        bb = __float2bfloat16(v.x); h.x = *(unsigned short*)&bb; r = v.x - __bfloat162float(bb);
        bb = __float2bfloat16(r);   l.x = *(unsigned short*)&bb;
        bb = __float2bfloat16(v.y); h.y = *(unsigned short*)&bb; r = v.y - __bfloat162float(bb);
        bb = __float2bfloat16(r);   l.y = *(unsigned short*)&bb;
        bb = __float2bfloat16(v.z); h.z = *(unsigned short*)&bb; r = v.z - __bfloat162float(bb);
        bb = __float2bfloat16(r);   l.z = *(unsigned short*)&bb;
        bb = __float2bfloat16(v.w); h.w = *(unsigned short*)&bb; r = v.w - __bfloat162float(bb);
        bb = __float2bfloat16(r);   l.w = *(unsigned short*)&bb;
        ((ushort4*)feathi)[idx] = h;
        ((ushort4*)featlo)[idx] = l;
        return;
    }
    b -= 2500;
    if (b < 256) {
        int bx = b >> 3, by = b & 7;
        int tx = tid & 31, ty = tid >> 5;
#pragma unroll
        for (int i = ty; i < 32; i += 8) {
            int k = by * 32 + i, c = bx * 32 + tx;
            float v;
            if (c < 256) v = W1a[k * 256 + c];
            else if (c < 512) v = W1e[k * 256 + c - 256];
            else if (c < 768) v = R1a[k * 256 + c - 512];
            else v = R1e[k * 256 + c - 768];
            sh[i * 33 + tx] = v;
        }
        __syncthreads();
#pragma unroll
        for (int i = ty; i < 32; i += 8) {
            float x = sh[tx * 33 + i];
            __hip_bfloat16 bh = __float2bfloat16(x);
            float r = x - __bfloat162float(bh);
            __hip_bfloat16 bl = __float2bfloat16(r);
            WThi[(size_t)(bx * 32 + i) * 256 + by * 32 + tx] = *(unsigned short*)&bh;
            WTlo[(size_t)(bx * 32 + i) * 256 + by * 32 + tx] = *(unsigned short*)&bl;
        }
        return;
    }
    b -= 256;
    if (b < 8) {
        float* frow = sh;
        float* red = sh + 256;
        int t = *tptr;
        frow[tid] = feat[t * 256 + tid];
        __syncthreads();
        int j = b * 64 + (tid & 63);
        int ks = (tid >> 6) * 64;
        float s = 0.f;
#pragma unroll 16
        for (int k = ks; k < ks + 64; ++k) s = fmaf(frow[k], Wt[(size_t)k * 512 + j], s);
        red[tid] = s;
        __syncthreads();
        if (tid < 64) {
            float v = red[tid] + red[tid + 64] + red[tid + 128] + red[tid + 192] + bt[j];
            tf[j] = v >= 0.f ? v : 0.01f * v;
        }
        return;
    }
    b -= 8;
    if (b < 2500) {
        int idx = b * 256 + tid;
        int it = idx / (16 * NGR);
        int f = idx - it * (16 * NGR);
        u32 fk0, fk1, o0, o1;
        threefry(0u, 42u, 0u, (u32)it, fk0, fk1);
        threefry(fk0, fk1, 0u, (u32)f, o0, o1);
        u32 bits = o0 ^ o1;
        float fl = __uint_as_float((bits >> 9) | 0x3F800000u) - 1.0f;
        float u = fmaxf(TINYF, fl + TINYF);
        gum[idx] = -logf(-logf(u));
        return;
    }
    b -= 2500;
    if (b < 16) {
        int o = b * 256 + tid;
        int k = o >> 3, q = o & 7, sel = q >> 2, hh = q & 3;
        const float* av = (sel ? ar2a : al2a) + hh * 256;
        const float* wr = W2a + (size_t)k * 1024 + hh * 256;
        float s = 0.f;
        for (int d = 0; d < 256; ++d) s = fmaf(wr[d], av[d], s);
        wal[k * 8 + q] = s;
        return;
    }
    b -= 16;
    if (b < 235) {
        int idx = b * 256 + tid;
        if (idx < NGR * 6) zreg[idx] = 0.f;
        return;
    }
    b -= 235;
    {
        int c = b * 256 + tid;
        packb[c] = (c < 512) ? 0.f : ((c < 768) ? b1a[c - 512] : b1e[c - 768]);
    }
}

// ---------- bf16x3 MFMA GEMM (f32-emulation): C = A @ BT^T + bias, K=256 ----------
__global__ __launch_bounds__(256) void gemm_bf16x3(
    const unsigned short* __restrict__ Ahi, const unsigned short* __restrict__ Alo,
    const unsigned short* __restrict__ Bhi, const unsigned short* __restrict__ Blo,
    float* __restrict__ C, const float* __restrict__ bias, int M)
{
    constexpr int K = 256;
    __shared__ unsigned short AsH[2][128 * 32];
    __shared__ unsigned short AsL[2][128 * 32];
    __shared__ unsigned short BsH[2][128 * 32];
    __shared__ unsigned short BsL[2][128 * 32];
    const int tid = threadIdx.x;
    const int lane = tid & 63;
    const int w = tid >> 6, wr = w >> 1, wc = w & 1;
    const int bm = blockIdx.y * 128, bn = blockIdx.x * 128;
    const int fr = lane & 15, fq = lane >> 4;
    const int srow = tid >> 2;
    const int sbyte = (tid & 3) * 16;
    f32x4 acc[4][4] = {};

    auto stage = [&](int b, int k0) {
        const char* pA[2] = {(const char*)Ahi, (const char*)Alo};
        const char* pB[2] = {(const char*)Bhi, (const char*)Blo};
        char* dA[2] = {(char*)AsH[b], (char*)AsL[b]};
        char* dB[2] = {(char*)BsH[b], (char*)BsL[b]};
#pragma unroll
        for (int q = 0; q < 2; ++q) {
            const char* ga0 = pA[q] + ((size_t)(bm + srow) * K + k0) * 2 + sbyte;
            const char* ga1 = pA[q] + ((size_t)(bm + 64 + srow) * K + k0) * 2 + sbyte;
            const char* gb0 = pB[q] + ((size_t)(bn + srow) * K + k0) * 2 + sbyte;
            const char* gb1 = pB[q] + ((size_t)(bn + 64 + srow) * K + k0) * 2 + sbyte;
            __builtin_amdgcn_global_load_lds((const __attribute__((address_space(1))) void*)ga0,
                (__attribute__((address_space(3))) void*)(dA[q] + tid * 16), 16, 0, 0);
            __builtin_amdgcn_global_load_lds((const __attribute__((address_space(1))) void*)ga1,
                (__attribute__((address_space(3))) void*)(dA[q] + 4096 + tid * 16), 16, 0, 0);
            __builtin_amdgcn_global_load_lds((const __attribute__((address_space(1))) void*)gb0,
                (__attribute__((address_space(3))) void*)(dB[q] + tid * 16), 16, 0, 0);
            __builtin_amdgcn_global_load_lds((const __attribute__((address_space(1))) void*)gb1,
                (__attribute__((address_space(3))) void*)(dB[q] + 4096 + tid * 16), 16, 0, 0);
        }
    };

    stage(0, 0);
    __syncthreads();
    int buf = 0;
    for (int t = 0; t < 8; ++t) {
        if (t < 7) stage(buf ^ 1, (t + 1) * 32);
        const char* ah = (const char*)AsH[buf];
        const char* al = (const char*)AsL[buf];
        const char* bh = (const char*)BsH[buf];
        const char* bl = (const char*)BsL[buf];
        short8 afh[4], afl[4], bfh[4], bfl[4];
#pragma unroll
        for (int m = 0; m < 4; ++m) {
            int o = (wr * 64 + m * 16 + fr) * 64 + fq * 16;
            afh[m] = *(const short8*)(ah + o);
            afl[m] = *(const short8*)(al + o);
        }
#pragma unroll
        for (int n = 0; n < 4; ++n) {
            int o = (wc * 64 + n * 16 + fr) * 64 + fq * 16;
            bfh[n] = *(const short8*)(bh + o);
            bfl[n] = *(const short8*)(bl + o);
        }
#pragma unroll
        for (int m = 0; m < 4; ++m)
#pragma unroll
            for (int n = 0; n < 4; ++n) {
                acc[m][n] = __builtin_amdgcn_mfma_f32_16x16x32_bf16(afl[m], bfh[n], acc[m][n], 0, 0, 0);
                acc[m][n] = __builtin_amdgcn_mfma_f32_16x16x32_bf16(afh[m], bfl[n], acc[m][n], 0, 0, 0);
                acc[m][n] = __builtin_amdgcn_mfma_f32_16x16x32_bf16(afh[m], bfh[n], acc[m][n], 0, 0, 0);
            }
        __syncthreads();
        buf ^= 1;
    }
#pragma unroll
    for (int m = 0; m < 4; ++m) {
#pragma unroll
        for (int i = 0; i < 4; ++i) {
            int row = bm + wr * 64 + m * 16 + fq * 4 + i;
            if (row >= M) continue;
#pragma unroll
            for (int n = 0; n < 4; ++n) {
                int col = bn + wc * 64 + n * 16 + fr;
                C[(size_t)row * 1024 + col] = acc[m][n][i] + bias[col];
            }
        }
    }
}

// ---------- L1 el/er for both heads ----------
__global__ void k_el_er_l1(const float* __restrict__ h,
                           const float* __restrict__ al1a, const float* __restrict__ ar1a,
                           const float* __restrict__ al1e, const float* __restrict__ ar1e,
                           float* __restrict__ el, float* __restrict__ er, int N)
{
    int idx = blockIdx.x * blockDim.x + threadIdx.x;
    if (idx >= N * 8) return;
    int n = idx >> 3, sub = idx & 7;
    int role = sub >> 2, hh = sub & 3;
    const float* hp = h + (size_t)n * 1024 + role * 256 + hh * 64;
    const float* alp = (role ? al1e : al1a) + hh * 64;
    const float* arp = (role ? ar1e : ar1a) + hh * 64;
    float sl = 0.f, sr = 0.f;
    for (int d = 0; d < 64; d += 4) {
        float4 v = *(const float4*)(hp + d);
        float4 a4 = *(const float4*)(alp + d);
        float4 r4 = *(const float4*)(arp + d);
        sl = fmaf(v.x, a4.x, sl); sl = fmaf(v.y, a4.y, sl); sl = fmaf(v.z, a4.z, sl); sl = fmaf(v.w, a4.w, sl);
        sr = fmaf(v.x, r4.x, sr); sr = fmaf(v.y, r4.y, sr); sr = fmaf(v.z, r4.z, sr); sr = fmaf(v.w, r4.w, sr);
    }
    el[n * 8 + sub] = sl;
    er[n * 8 + sub] = sr;
}

// ---------- CSR edge softmax (L1) ----------
__global__ void k_softmax_csr(const float* __restrict__ el, const float* __restrict__ er,
                              const int* __restrict__ rowptr, const int* __restrict__ colidx,
                              const int* __restrict__ src,
                              float* __restrict__ ee, int H, int hshift, int total)
{
    int idx = blockIdx.x * blockDim.x + threadIdx.x;
    if (idx >= total) return;
    int n = idx >> hshift, hh = idx & (H - 1);
    float ern = er[n * H + hh];
    int i0 = rowptr[n], i1 = rowptr[n + 1];
    float mx = -INFINITY;
    for (int i = i0; i < i1; ++i) {
        float v = el[src[colidx[i]] * H + hh] + ern;
        v = v >= 0.f ? v : 0.2f * v;
        mx = fmaxf(mx, v);
    }
    float s = 0.f;
    for (int i = i0; i < i1; ++i) {
        int e = colidx[i];
        float v = el[src[e] * H + hh] + ern;
        v = v >= 0.f ? v : 0.2f * v;
        float ex = expf(v - mx);
        ee[(size_t)e * H + hh] = ex;
        s += ex;
    }
    for (int i = i0; i < i1; ++i) {
        int e = colidx[i];
        ee[(size_t)e * H + hh] /= s;
    }
}

// ---------- fused L1 aggregation + a2/e2 epilogue ----------
__global__ void k_agg_a2e2(const float* __restrict__ alpha,
                           const int* __restrict__ rowptr, const int* __restrict__ colidx,
                           const int* __restrict__ src,
                           const float* __restrict__ regionA, const float* __restrict__ tf,
                           float* __restrict__ a2e2, int total)
{
    int idx = blockIdx.x * blockDim.x + threadIdx.x;
    if (idx >= total) return;
    int n = idx >> 7, c4 = idx & 127;
    int hh = c4 >> 4;
    const float4* h4 = (const float4*)regionA;
    float4 acc = h4[(size_t)n * 256 + 128 + c4];
    int i1 = rowptr[n + 1];
    for (int i = rowptr[n]; i < i1; ++i) {
        int e = colidx[i];
        float a = alpha[(size_t)e * 8 + hh];
        float4 hv = h4[(size_t)src[e] * 256 + c4];
        acc.x = fmaf(a, hv.x, acc.x); acc.y = fmaf(a, hv.y, acc.y);
        acc.z = fmaf(a, hv.z, acc.z); acc.w = fmaf(a, hv.w, acc.w);
    }
    int c = c4 << 2;
    int cc = (c + 256) & 511;
    float4 ta = *(const float4*)(tf + c);
    float4 te = *(const float4*)(tf + cc);
    float4 xa, xe;
    xa.x = acc.x + ta.x; xa.y = acc.y + ta.y; xa.z = acc.z + ta.z; xa.w = acc.w + ta.w;
    xe.x = acc.x + te.x; xe.y = acc.y + te.y; xe.z = acc.z + te.z; xe.w = acc.w + te.w;
    xa.x = xa.x >= 0.f ? xa.x : 0.01f * xa.x;
    xa.y = xa.y >= 0.f ? xa.y : 0.01f * xa.y;
    xa.z = xa.z >= 0.f ? xa.z : 0.01f * xa.z;
    xa.w = xa.w >= 0.f ? xa.w : 0.01f * xa.w;
    xe.x = xe.x >= 0.f ? xe.x : 0.01f * xe.x;
    xe.y = xe.y >= 0.f ? xe.y : 0.01f * xe.y;
    xe.z = xe.z >= 0.f ? xe.z : 0.01f * xe.z;
    xe.w = xe.w >= 0.f ? xe.w : 0.01f * xe.w;
    *(float4*)(a2e2 + (size_t)n * 1024 + c) = xa;
    *(float4*)(a2e2 + (size_t)n * 1024 + 512 + cc) = xe;
}

// ---------- node-linear v2 (inverted loops) ----------
__global__ __launch_bounds__(256) void k_node_linear(
    const float* __restrict__ a2e2,
    const float* __restrict__ We, const float* __restrict__ Re, const float* __restrict__ be,
    const float* __restrict__ wal,
    const float* __restrict__ al2e, const float* __restrict__ ar2e,
    float* __restrict__ h2e, float* __restrict__ e3,
    float* __restrict__ el2e, float* __restrict__ er2e,
    float* __restrict__ el2a, float* __restrict__ er2a)
{
    __shared__ float As[8 * 1024];
    __shared__ float red[2048];
    __shared__ float hl[8][16];
    int tid = threadIdx.x;
    int m0 = blockIdx.x * 8;
    for (int i = tid; i < 8 * 256; i += 256) {
        int row = i >> 8, c4 = (i & 255) << 2;
        *(float4*)(As + row * 1024 + c4) = *(const float4*)(a2e2 + (size_t)(m0 + row) * 1024 + c4);
    }
    __syncthreads();
    {
        int j = tid & 31, ks = tid >> 5;
        const float* B = (j < 16) ? We : Re;
        int jj = j & 15;
        float acc[8] = {};
        int k0 = ks * 64;
        for (int kk = 0; kk < 64; kk += 4) {
            int k = k0 + kk;
            float b0 = B[(k + 0) * 16 + jj];
            float b1 = B[(k + 1) * 16 + jj];
            float b2 = B[(k + 2) * 16 + jj];
            float b3 = B[(k + 3) * 16 + jj];
#pragma unroll
            for (int r = 0; r < 8; ++r) {
                float4 a = *(const float4*)(As + r * 1024 + 512 + k);
                acc[r] = fmaf(a.x, b0, acc[r]);
                acc[r] = fmaf(a.y, b1, acc[r]);
                acc[r] = fmaf(a.z, b2, acc[r]);
                acc[r] = fmaf(a.w, b3, acc[r]);
            }
        }
#pragma unroll
        for (int r = 0; r < 8; ++r) red[(r * 32 + j) * 8 + ks] = acc[r];
    }
    __syncthreads();
    {
        int r = tid >> 5, jo = tid & 31;
        const float* rp = red + (r * 32 + jo) * 8;
        float acc = ((rp[0] + rp[1]) + (rp[2] + rp[3])) + ((rp[4] + rp[5]) + (rp[6] + rp[7]));
        int m = m0 + r, jj = jo & 15;
        if (jo < 16) { h2e[(size_t)m * 16 + jj] = acc; hl[r][jj] = acc; }
        else         e3[(size_t)m * 16 + jj] = acc + be[jj];
    }
    __syncthreads();
    {
        int q = tid & 7, ks2 = tid >> 3;
        float acc[8] = {};
        int k0 = ks2 * 16;
        for (int kk = 0; kk < 16; ++kk) {
            int k = k0 + kk;
            float b = wal[k * 8 + q];
#pragma unroll
            for (int r = 0; r < 8; ++r)
                acc[r] = fmaf(As[r * 1024 + k], b, acc[r]);
        }
#pragma unroll
        for (int r = 0; r < 8; ++r) red[(r * 8 + q) * 32 + ks2] = acc[r];
    }
    __syncthreads();
    if (tid < 64) {
        const float* rp = red + tid * 32;
        float acc = 0.f;
#pragma unroll
        for (int g = 0; g < 32; ++g) acc += rp[g];
        int r = tid >> 3, q = tid & 7;
        int m = m0 + r;
        if (q < 4) el2a[m * 4 + q] = acc;
        else       er2a[m * 4 + (q - 4)] = acc;
    }
    if (tid >= 64 && tid < 72) {
        int rr = tid - 64;
        float sl = 0.f, sr = 0.f;
        const float* hp = hl[rr];
        for (int d = 0; d < 16; ++d) { float v = hp[d]; sl = fmaf(v, al2e[d], sl); sr = fmaf(v, ar2e[d], sr); }
        el2e[m0 + rr] = sl;
        er2e[m0 + rr] = sr;
    }
}

// ---------- fused L2 softmax: 2a+walpha (idx<N*4) | e-head agg (rest) ----------
__global__ void k_sm_l2(const float* __restrict__ el2a, const float* __restrict__ er2a,
                        const float* __restrict__ el2e, const float* __restrict__ er2e,
                        const int* __restrict__ rowptr, const int* __restrict__ colidx,
                        const int* __restrict__ src,
                        const float* __restrict__ h2e,
                        float* __restrict__ walpha, float* __restrict__ e3, int N)
{
    int idx = blockIdx.x * blockDim.x + threadIdx.x;
    if (idx < N * 4) {
        int n = idx >> 2, hh = idx & 3;
        float ern = er2a[n * 4 + hh];
        int i0 = rowptr[n], i1 = rowptr[n + 1];
        float mx = -INFINITY;
        for (int i = i0; i < i1; ++i) {
            float v = el2a[src[colidx[i]] * 4 + hh] + ern;
            v = v >= 0.f ? v : 0.2f * v;
            mx = fmaxf(mx, v);
        }
        float s = 0.f;
        for (int i = i0; i < i1; ++i) {
            float v = el2a[src[colidx[i]] * 4 + hh] + ern;
            v = v >= 0.f ? v : 0.2f * v;
            s += expf(v - mx);
        }
        for (int i = i0; i < i1; ++i) {
            int e = colidx[i];
            int sn = src[e];
            float v = el2a[sn * 4 + hh] + ern;
            v = v >= 0.f ? v : 0.2f * v;
            float alpha = expf(v - mx) / s;
            atomicAdd(&walpha[sn * 4 + hh], alpha);
        }
        return;
    }
    int n = idx - N * 4;
    if (n >= N) return;
    float ern = er2e[n];
    int i0 = rowptr[n], i1 = rowptr[n + 1];
    float mx = -INFINITY;
    for (int i = i0; i < i1; ++i) {
        float v = el2e[src[colidx[i]]] + ern;
        v = v >= 0.f ? v : 0.2f * v;
        mx = fmaxf(mx, v);
    }
    float s = 0.f;
    for (int i = i0; i < i1; ++i) {
        float v = el2e[src[colidx[i]]] + ern;
        v = v >= 0.f ? v : 0.2f * v;
        s += expf(v - mx);
    }
    float4* e34 = (float4*)(e3 + (size_t)n * 16);
    float4 a0 = e34[0], a1 = e34[1], a2 = e34[2], a3 = e34[3];
    for (int i = i0; i < i1; ++i) {
        int e = colidx[i];
        int sn = src[e];
        float v = el2e[sn] + ern;
        v = v >= 0.f ? v : 0.2f * v;
        float al = expf(v - mx) / s;
        const float4* hp = (const float4*)(h2e + (size_t)sn * 16);
        float4 h0 = hp[0], h1 = hp[1], h2 = hp[2], h3 = hp[3];
        a0.x = fmaf(al, h0.x, a0.x); a0.y = fmaf(al, h0.y, a0.y); a0.z = fmaf(al, h0.z, a0.z); a0.w = fmaf(al, h0.w, a0.w);
        a1.x = fmaf(al, h1.x, a1.x); a1.y = fmaf(al, h1.y, a1.y); a1.z = fmaf(al, h1.z, a1.z); a1.w = fmaf(al, h1.w, a1.w);
        a2.x = fmaf(al, h2.x, a2.x); a2.y = fmaf(al, h2.y, a2.y); a2.z = fmaf(al, h2.z, a2.z); a2.w = fmaf(al, h2.w, a2.w);
        a3.x = fmaf(al, h3.x, a3.x); a3.y = fmaf(al, h3.y, a3.y); a3.z = fmaf(al, h3.z, a3.z); a3.w = fmaf(al, h3.w, a3.w);
    }
    e34[0] = a0; e34[1] = a1; e34[2] = a2; e34[3] = a3;
}

// ---------- attr partials ----------
__global__ __launch_bounds__(256) void k_pwa(const float* __restrict__ a2e2,
                                             const float* __restrict__ walpha,
                                             float* __restrict__ pwa)
{
    int b = blockIdx.x, t = threadIdx.x;
    float acc[5][2] = {};
    int n0 = b * 80, n1 = min(n0 + 80, NGR);
    for (int n = n0; n < n1; ++n) {
        const float* row = a2e2 + (size_t)n * 1024;
        const float* wa = walpha + n * 4;
        float w0 = wa[0], w1 = wa[1], w2 = wa[2], w3 = wa[3];
        float x0 = row[t], x1 = row[t + 256];
        acc[0][0] = fmaf(w0, x0, acc[0][0]); acc[0][1] = fmaf(w0, x1, acc[0][1]);
        acc[1][0] = fmaf(w1, x0, acc[1][0]); acc[1][1] = fmaf(w1, x1, acc[1][1]);
        acc[2][0] = fmaf(w2, x0, acc[2][0]); acc[2][1] = fmaf(w2, x1, acc[2][1]);
        acc[3][0] = fmaf(w3, x0, acc[3][0]); acc[3][1] = fmaf(w3, x1, acc[3][1]);
        acc[4][0] += x0; acc[4][1] += x1;
    }
#pragma unroll
    for (int q = 0; q < 5; ++q) {
        pwa[(size_t)b * 2560 + q * 512 + t] = acc[q][0];
        pwa[(size_t)b * 2560 + q * 512 + t + 256] = acc[q][1];
    }
}
__global__ void k_pwa_fin(const float* __restrict__ pwa, float* __restrict__ waw)
{
    int idx = blockIdx.x * blockDim.x + threadIdx.x;
    if (idx >= 2560) return;
    float s = 0.f;
    for (int b = 0; b < 125; ++b) s += pwa[(size_t)b * 2560 + idx];
    waw[idx] = s;
}

// ---------- attr GEMV (64 blocks) ----------
__global__ __launch_bounds__(256) void k_gemv3(const float* __restrict__ waw,
                                               const float* __restrict__ W2a, const float* __restrict__ R2a,
                                               const float* __restrict__ b2a,
                                               float* __restrict__ attrL)
{
    __shared__ float red[256];
    int b = blockIdx.x, t = threadIdx.x;
    int c = b * 16 + (t & 15);
    int hh = (b * 16) >> 8;
    int ks = (t >> 4) * 32;
    const float* wh = waw + hh * 512;
    const float* w4 = waw + 4 * 512;
    float s = 0.f;
#pragma unroll 8
    for (int k = ks; k < ks + 32; ++k) {
        s = fmaf(wh[k], W2a[(size_t)k * 1024 + c], s);
        s = fmaf(w4[k], R2a[(size_t)k * 1024 + c], s);
    }
    red[t] = s;
    __syncthreads();
    if (t < 16) {
        float v = 0.f;
#pragma unroll
        for (int g = 0; g < 16; ++g) v += red[t + g * 16];
        v = v / (float)NGR + b2a[b * 16 + t];
        attrL[b * 16 + t] = v >= 0.f ? v : 0.01f * v;
    }
}

// ---------- node_attr ----------
__global__ __launch_bounds__(256) void k_nattr2(const float* __restrict__ attrL,
                                                const float* __restrict__ Wo, const float* __restrict__ bo,
                                                float* __restrict__ out)
{
    __shared__ float al[64];
    int i = blockIdx.x, t = threadIdx.x;
    if (t < 64) al[t] = attrL[i * 64 + t];
    __syncthreads();
    float acc = 0.f;
#pragma unroll 8
    for (int d = 0; d < 64; ++d) acc = fmaf(al[d], Wo[d * 256 + t], acc);
    acc += bo[t];
    out[i * 256 + t] = acc;
    out[4096 + i * 256 + t] = acc;
}

// ---------- sampler stage 1: chunked softmax stats ----------
__global__ __launch_bounds__(256) void k_e3stats(const float* __restrict__ e3,
                                                 float* __restrict__ pm, float* __restrict__ ps)
{
    __shared__ float lds[4000];
    __shared__ float redm[16][16];
    __shared__ float reds[16][16];
    __shared__ float cm[16];
    int b = blockIdx.x, tid = threadIdx.x;
    int base = b * 250 * 16;
    for (int i = tid; i < 4000; i += 256) lds[i] = e3[base + i];
    __syncthreads();
    int c = tid & 15, g = tid >> 4;
    float mx = -INFINITY;
    for (int q = g; q < 250; q += 16) mx = fmaxf(mx, lds[q * 16 + c]);
    redm[c][g] = mx;
    __syncthreads();
    if (tid < 16) {
        float m = redm[tid][0];
        for (int q = 1; q < 16; ++q) m = fmaxf(m, redm[tid][q]);
        cm[tid] = m;
    }
    __syncthreads();
    float mb = cm[c];
    float s = 0.f;
    for (int q = g; q < 250; q += 16) s += expf(lds[q * 16 + c] - mb);
    reds[c][g] = s;
    __syncthreads();
    if (tid < 16) {
        float ss = 0.f;
        for (int q = 0; q < 16; ++q) ss += reds[tid][q];
        pm[b * 16 + tid] = cm[tid];
        ps[b * 16 + tid] = ss;
    }
}

// ---------- sampler stage 2: top-5 of g + p per (it,r,chunk); e3fin folded in ----------
__global__ __launch_bounds__(256) void k_top5(const float* __restrict__ e3, const float* __restrict__ gum,
                                              const float* __restrict__ pm, const float* __restrict__ ps,
                                              float* __restrict__ probs,
                                              float* __restrict__ t5v, int* __restrict__ t5i)
{
    __shared__ float wv[4];
    __shared__ int wi[4];
    int chunk = blockIdx.x, y = blockIdx.y;
    int it = y >> 4, r = y & 15;
    int tid = threadIdx.x, lane = tid & 63, wid = tid >> 6;
    float M = -INFINITY;
    for (int b = 0; b < 40; ++b) M = fmaxf(M, pm[b * 16 + r]);
    float S = 0.f;
    for (int b = 0; b < 40; ++b) S += ps[b * 16 + r] * expf(pm[b * 16 + r] - M);
    float mxr = M, ssr = S;
    const float* g = gum + (size_t)y * NGR;
    int jb = chunk * 1250;
    float sv[5]; int si[5];
#pragma unroll
    for (int q = 0; q < 5; ++q) {
        int o = q * 256 + tid;
        float s = -INFINITY; int idx = 0x7FFFFFFF;
        if (o < 1250) {
            int j = jb + o;
            float p = expf(e3[(size_t)j * 16 + r] - mxr) / ssr;
            if (it == 0) probs[(size_t)r * NGR + j] = p;
            s = g[j] + p;
            idx = j;
        }
        sv[q] = s; si[q] = idx;
    }
    int outb = (y * 8 + chunk) * 5;
    for (int round = 0; round < 5; ++round) {
        float best = sv[0]; int bi = si[0];
#pragma unroll
        for (int q = 1; q < 5; ++q)
            if (sv[q] > best || (sv[q] == best && si[q] < bi)) { best = sv[q]; bi = si[q]; }
#pragma unroll
        for (int o = 32; o > 0; o >>= 1) {
            float ov = __shfl_xor(best, o, 64); int oi = __shfl_xor(bi, o, 64);
            if (ov > best || (ov == best && oi < bi)) { best = ov; bi = oi; }
        }
        if (lane == 0) { wv[wid] = best; wi[wid] = bi; }
        __syncthreads();
        float gbv = wv[0]; int gbi = wi[0];
#pragma unroll
        for (int w2 = 1; w2 < 4; ++w2) {
            float ov = wv[w2]; int oi = wi[w2];
            if (ov > gbv || (ov == gbv && oi < gbi)) { gbv = ov; gbi = oi; }
        }
        if (tid == 0) { t5v[outb + round] = gbv; t5i[outb + round] = gbi; }
#pragma unroll
        for (int q = 0; q < 5; ++q) if (si[q] == gbi) { sv[q] = -INFINITY; si[q] = 0x7FFFFFFF; }
        __syncthreads();
    }
}

// ---------- sampler stage 3: sequential exclusion ----------
__global__ void k_select(const int* __restrict__ tptr, const float* __restrict__ t5v,
                         const int* __restrict__ t5i, float* __restrict__ out_edges)
{
    int r = threadIdx.x;
    if (r >= 16) return;
    int s0 = *tptr, s1 = -1, s2 = -1, s3 = -1;
    out_edges[r * 5] = (float)s0;
    for (int it = 0; it < 4; ++it) {
        float best = -INFINITY; int bi = 0x7FFFFFFF;
        int base = (it * 16 + r) * 40;
        for (int c = 0; c < 40; ++c) {
            int idx = t5i[base + c];
            if (idx == s0 || idx == s1 || idx == s2 || idx == s3) continue;
            float v = t5v[base + c];
            if (v > best || (v == best && idx < bi)) { best = v; bi = idx; }
        }
        if (it == 0) s1 = bi; else if (it == 1) s2 = bi; else if (it == 2) s3 = bi;
        out_edges[r * 5 + it + 1] = (float)bi;
    }
}

extern "C" void kernel_launch(void* const* d_in, const int* in_sizes, int n_in,
                              void* d_out, int out_size, void* d_ws, size_t ws_size,
                              hipStream_t stream)
{
    const float* feat = (const float*)d_in[0];
    const int* src = (const int*)d_in[1];
    const int* dst = (const int*)d_in[2];
    const int* tptr = (const int*)d_in[3];
    const float* W1a = (const float*)d_in[4];  const float* al1a = (const float*)d_in[5];
    const float* ar1a = (const float*)d_in[6]; const float* R1a = (const float*)d_in[7];
    const float* b1a = (const float*)d_in[8];
    const float* W1e = (const float*)d_in[9];  const float* al1e = (const float*)d_in[10];
    const float* ar1e = (const float*)d_in[11]; const float* R1e = (const float*)d_in[12];
    const float* b1e = (const float*)d_in[13];
    const float* W2a = (const float*)d_in[14]; const float* al2a = (const float*)d_in[15];
    const float* ar2a = (const float*)d_in[16]; const float* R2a = (const float*)d_in[17];
    const float* b2a = (const float*)d_in[18];
    const float* W2e = (const float*)d_in[19]; const float* al2e = (const float*)d_in[20];
    const float* ar2e = (const float*)d_in[21]; const float* R2e = (const float*)d_in[22];
    const float* b2e = (const float*)d_in[23];
    const float* Wt = (const float*)d_in[24];  const float* bt = (const float*)d_in[25];
    const float* Wo = (const float*)d_in[26];  const float* bo = (const float*)d_in[27];
    const int E = in_sizes[1];
    const int N = NGR;

    float* ws = (float*)d_ws;
    float* regionA = ws;
    size_t off = (size_t)N * 1024;
    auto alloc = [&](size_t n) { float* p = ws + off; off += (n + 3) & ~(size_t)3; return p; };
    float* a2e2 = alloc((size_t)N * 1024);
    float* tf   = alloc(512);
    float* el1  = alloc((size_t)N * 8);
    float* er1  = alloc((size_t)N * 8);
    float* el2a = alloc((size_t)N * 4);
    float* er2a = alloc((size_t)N * 4);
    float* el2e = alloc(N);
    float* er2e = alloc(N);
    float* h2e  = alloc((size_t)N * 16);
    float* e3   = alloc((size_t)N * 16);
    float* ee1  = alloc((size_t)E * 8);
    float* packb = alloc(1024);
    float* gum   = alloc((size_t)4 * 16 * NGR);
    float* wal   = alloc(512 * 8);
    float* pwa   = alloc(125 * 2560);
    float* waw   = alloc(2560);
    float* attrL = alloc(1024);
    float* pm    = alloc(40 * 16);
    float* ps    = alloc(40 * 16);
    float* t5v   = alloc(64 * 40);
    int*   t5i   = (int*)alloc(64 * 40);
    unsigned short* feathi = (unsigned short*)alloc((size_t)10112 * 128);
    unsigned short* featlo = (unsigned short*)alloc((size_t)10112 * 128);
    unsigned short* WThi = (unsigned short*)alloc((size_t)1024 * 128);
    unsigned short* WTlo = (unsigned short*)alloc((size_t)1024 * 128);
    float* zstart = alloc((size_t)N * 6);
    float* walpha = zstart;
    int* deg    = (int*)(zstart + (size_t)N * 4);
    int* cursor = deg + N;
    int* rowptr = (int*)alloc(N + 1);
    int* colidx = (int*)alloc(E);

    float* out = (float*)d_out;
    float* out_edges = out + 8192;
    float* out_probs = out + 8272;

    dim3 blk(256);

    k_prep<<<5519, blk, 0, stream>>>(feat, tptr, Wt, bt, W1a, W1e, R1a, R1e, b1a, b1e,
                                     W2a, al2a, ar2a, feathi, featlo, WThi, WTlo,
                                     tf, gum, wal, packb, zstart);
    k_deg<<<(E + 255) / 256, blk, 0, stream>>>(dst, deg, E);
    k_scan<<<1, blk, 0, stream>>>(deg, rowptr, N);
    k_scatter<<<(E + 255) / 256, blk, 0, stream>>>(dst, rowptr, cursor, colidx, E);

    gemm_bf16x3<<<dim3(8, 79), blk, 0, stream>>>(feathi, featlo, WThi, WTlo, regionA, packb, N);
    k_el_er_l1<<<(N * 8 + 255) / 256, blk, 0, stream>>>(regionA, al1a, ar1a, al1e, ar1e, el1, er1, N);
    k_softmax_csr<<<(N * 8 + 255) / 256, blk, 0, stream>>>(el1, er1, rowptr, colidx, src, ee1, 8, 3, N * 8);
    k_agg_a2e2<<<(N * 128 + 255) / 256, blk, 0, stream>>>(ee1, rowptr, colidx, src,
                                                          regionA, tf, a2e2, N * 128);

    k_node_linear<<<N / 8, blk, 0, stream>>>(a2e2, W2e, R2e, b2e, wal, al2e, ar2e,
                                             h2e, e3, el2e, er2e, el2a, er2a);
    k_sm_l2<<<(N * 5 + 255) / 256, blk, 0, stream>>>(el2a, er2a, el2e, er2e,
                                                     rowptr, colidx, src, h2e, walpha, e3, N);

    k_pwa<<<125, blk, 0, stream>>>(a2e2, walpha, pwa);
    k_pwa_fin<<<10, blk, 0, stream>>>(pwa, waw);
    k_gemv3<<<64, blk, 0, stream>>>(waw, W2a, R2a, b2a, attrL);
    k_nattr2<<<16, blk, 0, stream>>>(attrL, Wo, bo, out);

    k_e3stats<<<40, blk, 0, stream>>>(e3, pm, ps);
    k_top5<<<dim3(8, 64), blk, 0, stream>>>(e3, gum, pm, ps, out_probs, t5v, t5i);
    k_select<<<1, 64, 0, stream>>>(tptr, t5v, t5i, out_edges);
}

// Round 15
// 314.169 us; speedup vs baseline: 1.0272x; 1.0272x over previous
//
#include <hip/hip_runtime.h>
#include <hip/hip_bf16.h>

#define NGR 10000
typedef unsigned int u32;
typedef __attribute__((ext_vector_type(8))) short short8;
typedef __attribute__((ext_vector_type(4))) float f32x4;

// ---------- threefry2x32 (JAX-exact) ----------
__device__ __forceinline__ void threefry(u32 k0, u32 k1, u32 c0, u32 c1, u32& o0, u32& o1) {
    u32 ks2 = k0 ^ k1 ^ 0x1BD11BDAu;
    u32 x0 = c0 + k0, x1 = c1 + k1;
#define TF_R(r) { x0 += x1; x1 = (x1 << r) | (x1 >> (32 - r)); x1 ^= x0; }
    TF_R(13) TF_R(15) TF_R(26) TF_R(6)
    x0 += k1; x1 += ks2 + 1u;
    TF_R(17) TF_R(29) TF_R(16) TF_R(24)
    x0 += ks2; x1 += k0 + 2u;
    TF_R(13) TF_R(15) TF_R(26) TF_R(6)
    x0 += k0; x1 += k1 + 3u;
    TF_R(17) TF_R(29) TF_R(16) TF_R(24)
    x0 += k1; x1 += ks2 + 4u;
    TF_R(13) TF_R(15) TF_R(26) TF_R(6)
    x0 += ks2; x1 += k0 + 5u;
#undef TF_R
    o0 = x0; o1 = x1;
}

// ---------- CSR build ----------
__global__ void k_deg(const int* __restrict__ dst, int* __restrict__ deg, int E) {
    int i = blockIdx.x * blockDim.x + threadIdx.x;
    if (i < E) atomicAdd(&deg[dst[i]], 1);
}
__global__ void k_scan(const int* __restrict__ deg, int* __restrict__ rowptr, int n) {
    __shared__ int sums[256];
    __shared__ int excl[257];
    const int T = 256;
    int t = threadIdx.x;
    int per = (n + T - 1) / T;
    int lo = t * per, hi = min(lo + per, n);
    int s = 0;
    for (int i = lo; i < hi; ++i) s += deg[i];
    sums[t] = s;
    __syncthreads();
    if (t == 0) { int run = 0; for (int i = 0; i < T; ++i) { excl[i] = run; run += sums[i]; } excl[T] = run; }
    __syncthreads();
    int run = excl[t];
    for (int i = lo; i < hi; ++i) { rowptr[i] = run; run += deg[i]; }
    if (t == 0) rowptr[n] = excl[T];
}
__global__ void k_scatter(const int* __restrict__ dst, const int* __restrict__ rowptr,
                          int* __restrict__ cursor, int* __restrict__ colidx, int E) {
    int i = blockIdx.x * blockDim.x + threadIdx.x;
    if (i >= E) return;
    int d = dst[i];
    int pos = atomicAdd(&cursor[d], 1);
    colidx[rowptr[d] + pos] = i;
}

// ---------- mega-prep ----------
#define TINYF 1.17549435e-38f
__global__ __launch_bounds__(256) void k_prep(
    const float* __restrict__ feat, const int* __restrict__ tptr,
    const float* __restrict__ Wt, const float* __restrict__ bt,
    const float* __restrict__ W1a, const float* __restrict__ W1e,
    const float* __restrict__ R1a, const float* __restrict__ R1e,
    const float* __restrict__ b1a, const float* __restrict__ b1e,
    const float* __restrict__ W2a, const float* __restrict__ al2a, const float* __restrict__ ar2a,
    unsigned short* __restrict__ feathi, unsigned short* __restrict__ featlo,
    unsigned short* __restrict__ WThi, unsigned short* __restrict__ WTlo,
    float* __restrict__ tf, float* __restrict__ gum, float* __restrict__ wal,
    float* __restrict__ packb, float* __restrict__ zreg)
{
    __shared__ float sh[32 * 33];
    int b = blockIdx.x, tid = threadIdx.x;
    if (b < 2500) {
        int idx = b * 256 + tid;
        float4 v = ((const float4*)feat)[idx];
        ushort4 h, l;
        __hip_bfloat16 bb; float r;
        bb = __float2bfloat16(v.x); h.x = *(unsigned short*)&bb; r = v.x - __bfloat162float(bb);
        bb = __float2bfloat16(r);   l.x = *(unsigned short*)&bb;
        bb = __float2bfloat16(v.y); h.y = *(unsigned short*)&bb; r = v.y - __bfloat162float(bb);
        bb = __float2bfloat16(r);   l.y = *(unsigned short*)&bb;
        bb = __float2bfloat16(v.z); h.z = *(unsigned short*)&bb; r = v.z - __bfloat162float(bb);
        bb = __float2bfloat16(r);   l.z = *(unsigned short*)&bb;
        bb = __float2bfloat16(v.w); h.w = *(unsigned short*)&bb; r = v.w - __bfloat162float(bb);
        bb = __float2bfloat16(r);   l.w = *(unsigned short*)&bb;
        ((ushort4*)feathi)[idx] = h;
        ((ushort4*)featlo)[idx] = l;
        return;
    }
    b -= 2500;
    if (b < 256) {
        int bx = b >> 3, by = b & 7;
        int tx = tid & 31, ty = tid >> 5;
#pragma unroll
        for (int i = ty; i < 32; i += 8) {
            int k = by * 32 + i, c = bx * 32 + tx;
            float v;
            if (c < 256) v = W1a[k * 256 + c];
            else if (c < 512) v = W1e[k * 256 + c - 256];
            else if (c < 768) v = R1a[k * 256 + c - 512];
            else v = R1e[k * 256 + c - 768];
            sh[i * 33 + tx] = v;
        }
        __syncthreads();
#pragma unroll
        for (int i = ty; i < 32; i += 8) {
            float x = sh[tx * 33 + i];
            __hip_bfloat16 bh = __float2bfloat16(x);
            float r = x - __bfloat162float(bh);
            __hip_bfloat16 bl = __float2bfloat16(r);
            WThi[(size_t)(bx * 32 + i) * 256 + by * 32 + tx] = *(unsigned short*)&bh;
            WTlo[(size_t)(bx * 32 + i) * 256 + by * 32 + tx] = *(unsigned short*)&bl;
        }
        return;
    }
    b -= 256;
    if (b < 8) {
        float* frow = sh;
        float* red = sh + 256;
        int t = *tptr;
        frow[tid] = feat[t * 256 + tid];
        __syncthreads();
        int j = b * 64 + (tid & 63);
        int ks = (tid >> 6) * 64;
        float s = 0.f;
#pragma unroll 16
        for (int k = ks; k < ks + 64; ++k) s = fmaf(frow[k], Wt[(size_t)k * 512 + j], s);
        red[tid] = s;
        __syncthreads();
        if (tid < 64) {
            float v = red[tid] + red[tid + 64] + red[tid + 128] + red[tid + 192] + bt[j];
            tf[j] = v >= 0.f ? v : 0.01f * v;
        }
        return;
    }
    b -= 8;
    if (b < 2500) {
        int idx = b * 256 + tid;
        int it = idx / (16 * NGR);
        int f = idx - it * (16 * NGR);
        u32 fk0, fk1, o0, o1;
        threefry(0u, 42u, 0u, (u32)it, fk0, fk1);
        threefry(fk0, fk1, 0u, (u32)f, o0, o1);
        u32 bits = o0 ^ o1;
        float fl = __uint_as_float((bits >> 9) | 0x3F800000u) - 1.0f;
        float u = fmaxf(TINYF, fl + TINYF);
        gum[idx] = -logf(-logf(u));
        return;
    }
    b -= 2500;
    if (b < 16) {
        int o = b * 256 + tid;
        int k = o >> 3, q = o & 7, sel = q >> 2, hh = q & 3;
        const float* av = (sel ? ar2a : al2a) + hh * 256;
        const float* wr = W2a + (size_t)k * 1024 + hh * 256;
        float s = 0.f;
        for (int d = 0; d < 256; ++d) s = fmaf(wr[d], av[d], s);
        wal[k * 8 + q] = s;
        return;
    }
    b -= 16;
    if (b < 235) {
        int idx = b * 256 + tid;
        if (idx < NGR * 6) zreg[idx] = 0.f;
        return;
    }
    b -= 235;
    {
        int c = b * 256 + tid;
        packb[c] = (c < 512) ? 0.f : ((c < 768) ? b1a[c - 512] : b1e[c - 768]);
    }
}

// ---------- bf16x3 MFMA GEMM (f32-emulation): C = A @ BT^T + bias, K=256 ----------
__global__ __launch_bounds__(256) void gemm_bf16x3(
    const unsigned short* __restrict__ Ahi, const unsigned short* __restrict__ Alo,
    const unsigned short* __restrict__ Bhi, const unsigned short* __restrict__ Blo,
    float* __restrict__ C, const float* __restrict__ bias, int M)
{
    constexpr int K = 256;
    __shared__ unsigned short AsH[2][128 * 32];
    __shared__ unsigned short AsL[2][128 * 32];
    __shared__ unsigned short BsH[2][128 * 32];
    __shared__ unsigned short BsL[2][128 * 32];
    const int tid = threadIdx.x;
    const int lane = tid & 63;
    const int w = tid >> 6, wr = w >> 1, wc = w & 1;
    const int bm = blockIdx.y * 128, bn = blockIdx.x * 128;
    const int fr = lane & 15, fq = lane >> 4;
    const int srow = tid >> 2;
    const int sbyte = (tid & 3) * 16;
    f32x4 acc[4][4] = {};

    auto stage = [&](int b, int k0) {
        const char* pA[2] = {(const char*)Ahi, (const char*)Alo};
        const char* pB[2] = {(const char*)Bhi, (const char*)Blo};
        char* dA[2] = {(char*)AsH[b], (char*)AsL[b]};
        char* dB[2] = {(char*)BsH[b], (char*)BsL[b]};
#pragma unroll
        for (int q = 0; q < 2; ++q) {
            const char* ga0 = pA[q] + ((size_t)(bm + srow) * K + k0) * 2 + sbyte;
            const char* ga1 = pA[q] + ((size_t)(bm + 64 + srow) * K + k0) * 2 + sbyte;
            const char* gb0 = pB[q] + ((size_t)(bn + srow) * K + k0) * 2 + sbyte;
            const char* gb1 = pB[q] + ((size_t)(bn + 64 + srow) * K + k0) * 2 + sbyte;
            __builtin_amdgcn_global_load_lds((const __attribute__((address_space(1))) void*)ga0,
                (__attribute__((address_space(3))) void*)(dA[q] + tid * 16), 16, 0, 0);
            __builtin_amdgcn_global_load_lds((const __attribute__((address_space(1))) void*)ga1,
                (__attribute__((address_space(3))) void*)(dA[q] + 4096 + tid * 16), 16, 0, 0);
            __builtin_amdgcn_global_load_lds((const __attribute__((address_space(1))) void*)gb0,
                (__attribute__((address_space(3))) void*)(dB[q] + tid * 16), 16, 0, 0);
            __builtin_amdgcn_global_load_lds((const __attribute__((address_space(1))) void*)gb1,
                (__attribute__((address_space(3))) void*)(dB[q] + 4096 + tid * 16), 16, 0, 0);
        }
    };

    stage(0, 0);
    __syncthreads();
    int buf = 0;
    for (int t = 0; t < 8; ++t) {
        if (t < 7) stage(buf ^ 1, (t + 1) * 32);
        const char* ah = (const char*)AsH[buf];
        const char* al = (const char*)AsL[buf];
        const char* bh = (const char*)BsH[buf];
        const char* bl = (const char*)BsL[buf];
        short8 afh[4], afl[4], bfh[4], bfl[4];
#pragma unroll
        for (int m = 0; m < 4; ++m) {
            int o = (wr * 64 + m * 16 + fr) * 64 + fq * 16;
            afh[m] = *(const short8*)(ah + o);
            afl[m] = *(const short8*)(al + o);
        }
#pragma unroll
        for (int n = 0; n < 4; ++n) {
            int o = (wc * 64 + n * 16 + fr) * 64 + fq * 16;
            bfh[n] = *(const short8*)(bh + o);
            bfl[n] = *(const short8*)(bl + o);
        }
#pragma unroll
        for (int m = 0; m < 4; ++m)
#pragma unroll
            for (int n = 0; n < 4; ++n) {
                acc[m][n] = __builtin_amdgcn_mfma_f32_16x16x32_bf16(afl[m], bfh[n], acc[m][n], 0, 0, 0);
                acc[m][n] = __builtin_amdgcn_mfma_f32_16x16x32_bf16(afh[m], bfl[n], acc[m][n], 0, 0, 0);
                acc[m][n] = __builtin_amdgcn_mfma_f32_16x16x32_bf16(afh[m], bfh[n], acc[m][n], 0, 0, 0);
            }
        __syncthreads();
        buf ^= 1;
    }
#pragma unroll
    for (int m = 0; m < 4; ++m) {
#pragma unroll
        for (int i = 0; i < 4; ++i) {
            int row = bm + wr * 64 + m * 16 + fq * 4 + i;
            if (row >= M) continue;
#pragma unroll
            for (int n = 0; n < 4; ++n) {
                int col = bn + wc * 64 + n * 16 + fr;
                C[(size_t)row * 1024 + col] = acc[m][n][i] + bias[col];
            }
        }
    }
}

// ---------- L1 el/er for both heads ----------
__global__ void k_el_er_l1(const float* __restrict__ h,
                           const float* __restrict__ al1a, const float* __restrict__ ar1a,
                           const float* __restrict__ al1e, const float* __restrict__ ar1e,
                           float* __restrict__ el, float* __restrict__ er, int N)
{
    int idx = blockIdx.x * blockDim.x + threadIdx.x;
    if (idx >= N * 8) return;
    int n = idx >> 3, sub = idx & 7;
    int role = sub >> 2, hh = sub & 3;
    const float* hp = h + (size_t)n * 1024 + role * 256 + hh * 64;
    const float* alp = (role ? al1e : al1a) + hh * 64;
    const float* arp = (role ? ar1e : ar1a) + hh * 64;
    float sl = 0.f, sr = 0.f;
    for (int d = 0; d < 64; d += 4) {
        float4 v = *(const float4*)(hp + d);
        float4 a4 = *(const float4*)(alp + d);
        float4 r4 = *(const float4*)(arp + d);
        sl = fmaf(v.x, a4.x, sl); sl = fmaf(v.y, a4.y, sl); sl = fmaf(v.z, a4.z, sl); sl = fmaf(v.w, a4.w, sl);
        sr = fmaf(v.x, r4.x, sr); sr = fmaf(v.y, r4.y, sr); sr = fmaf(v.z, r4.z, sr); sr = fmaf(v.w, r4.w, sr);
    }
    el[n * 8 + sub] = sl;
    er[n * 8 + sub] = sr;
}

// ---------- CSR edge softmax (L1) ----------
__global__ void k_softmax_csr(const float* __restrict__ el, const float* __restrict__ er,
                              const int* __restrict__ rowptr, const int* __restrict__ colidx,
                              const int* __restrict__ src,
                              float* __restrict__ ee, int H, int hshift, int total)
{
    int idx = blockIdx.x * blockDim.x + threadIdx.x;
    if (idx >= total) return;
    int n = idx >> hshift, hh = idx & (H - 1);
    float ern = er[n * H + hh];
    int i0 = rowptr[n], i1 = rowptr[n + 1];
    float mx = -INFINITY;
    for (int i = i0; i < i1; ++i) {
        float v = el[src[colidx[i]] * H + hh] + ern;
        v = v >= 0.f ? v : 0.2f * v;
        mx = fmaxf(mx, v);
    }
    float s = 0.f;
    for (int i = i0; i < i1; ++i) {
        int e = colidx[i];
        float v = el[src[e] * H + hh] + ern;
        v = v >= 0.f ? v : 0.2f * v;
        float ex = expf(v - mx);
        ee[(size_t)e * H + hh] = ex;
        s += ex;
    }
    for (int i = i0; i < i1; ++i) {
        int e = colidx[i];
        ee[(size_t)e * H + hh] /= s;
    }
}

// ---------- L1 aggregation -> raw accumulator (2-way MLP unroll, FMA order preserved) ----------
__global__ void k_agg_acc(const float* __restrict__ alpha,
                          const int* __restrict__ rowptr, const int* __restrict__ colidx,
                          const int* __restrict__ src,
                          const float* __restrict__ regionA,
                          float* __restrict__ accb, int total)
{
    int idx = blockIdx.x * blockDim.x + threadIdx.x;
    if (idx >= total) return;
    int n = idx >> 7, c4 = idx & 127;
    int hh = c4 >> 4;
    const float4* h4 = (const float4*)regionA;
    float4 acc = h4[(size_t)n * 256 + 128 + c4];
    int i = rowptr[n], i1 = rowptr[n + 1];
    for (; i + 1 < i1; i += 2) {
        int e0 = colidx[i], e1 = colidx[i + 1];
        int s0 = src[e0], s1 = src[e1];
        float a0 = alpha[(size_t)e0 * 8 + hh];
        float a1 = alpha[(size_t)e1 * 8 + hh];
        float4 h0 = h4[(size_t)s0 * 256 + c4];
        float4 h1 = h4[(size_t)s1 * 256 + c4];
        acc.x = fmaf(a0, h0.x, acc.x); acc.y = fmaf(a0, h0.y, acc.y);
        acc.z = fmaf(a0, h0.z, acc.z); acc.w = fmaf(a0, h0.w, acc.w);
        acc.x = fmaf(a1, h1.x, acc.x); acc.y = fmaf(a1, h1.y, acc.y);
        acc.z = fmaf(a1, h1.z, acc.z); acc.w = fmaf(a1, h1.w, acc.w);
    }
    if (i < i1) {
        int e0 = colidx[i];
        float a0 = alpha[(size_t)e0 * 8 + hh];
        float4 h0 = h4[(size_t)src[e0] * 256 + c4];
        acc.x = fmaf(a0, h0.x, acc.x); acc.y = fmaf(a0, h0.y, acc.y);
        acc.z = fmaf(a0, h0.z, acc.z); acc.w = fmaf(a0, h0.w, acc.w);
    }
    ((float4*)accb)[(size_t)n * 128 + c4] = acc;
}

// ---------- node-linear v2: reconstructs a2/e2 from acc+tf (bit-identical) ----------
__global__ __launch_bounds__(256) void k_node_linear(
    const float* __restrict__ accb, const float* __restrict__ tf,
    const float* __restrict__ We, const float* __restrict__ Re, const float* __restrict__ be,
    const float* __restrict__ wal,
    const float* __restrict__ al2e, const float* __restrict__ ar2e,
    float* __restrict__ h2e, float* __restrict__ e3,
    float* __restrict__ el2e, float* __restrict__ er2e,
    float* __restrict__ el2a, float* __restrict__ er2a)
{
    __shared__ float As[8 * 1024];
    __shared__ float red[2048];
    __shared__ float hl[8][16];
    int tid = threadIdx.x;
    int m0 = blockIdx.x * 8;
    // load acc rows, build a2 (cols 0..511) and e2 (cols 512..1023)
    for (int i = tid; i < 8 * 128; i += 256) {
        int row = i >> 7, c = (i & 127) << 2;
        float4 a = *(const float4*)(accb + (size_t)(m0 + row) * 512 + c);
        int cc = (c + 256) & 511;
        float4 ta = *(const float4*)(tf + c);
        float4 te = *(const float4*)(tf + cc);
        float4 xa, xe;
        xa.x = a.x + ta.x; xa.y = a.y + ta.y; xa.z = a.z + ta.z; xa.w = a.w + ta.w;
        xe.x = a.x + te.x; xe.y = a.y + te.y; xe.z = a.z + te.z; xe.w = a.w + te.w;
        xa.x = xa.x >= 0.f ? xa.x : 0.01f * xa.x;
        xa.y = xa.y >= 0.f ? xa.y : 0.01f * xa.y;
        xa.z = xa.z >= 0.f ? xa.z : 0.01f * xa.z;
        xa.w = xa.w >= 0.f ? xa.w : 0.01f * xa.w;
        xe.x = xe.x >= 0.f ? xe.x : 0.01f * xe.x;
        xe.y = xe.y >= 0.f ? xe.y : 0.01f * xe.y;
        xe.z = xe.z >= 0.f ? xe.z : 0.01f * xe.z;
        xe.w = xe.w >= 0.f ? xe.w : 0.01f * xe.w;
        *(float4*)(As + row * 1024 + c) = xa;
        *(float4*)(As + row * 1024 + 512 + cc) = xe;
    }
    __syncthreads();
    {
        int j = tid & 31, ks = tid >> 5;
        const float* B = (j < 16) ? We : Re;
        int jj = j & 15;
        float acc[8] = {};
        int k0 = ks * 64;
        for (int kk = 0; kk < 64; kk += 4) {
            int k = k0 + kk;
            float b0 = B[(k + 0) * 16 + jj];
            float b1 = B[(k + 1) * 16 + jj];
            float b2 = B[(k + 2) * 16 + jj];
            float b3 = B[(k + 3) * 16 + jj];
#pragma unroll
            for (int r = 0; r < 8; ++r) {
                float4 a = *(const float4*)(As + r * 1024 + 512 + k);
                acc[r] = fmaf(a.x, b0, acc[r]);
                acc[r] = fmaf(a.y, b1, acc[r]);
                acc[r] = fmaf(a.z, b2, acc[r]);
                acc[r] = fmaf(a.w, b3, acc[r]);
            }
        }
#pragma unroll
        for (int r = 0; r < 8; ++r) red[(r * 32 + j) * 8 + ks] = acc[r];
    }
    __syncthreads();
    {
        int r = tid >> 5, jo = tid & 31;
        const float* rp = red + (r * 32 + jo) * 8;
        float acc = ((rp[0] + rp[1]) + (rp[2] + rp[3])) + ((rp[4] + rp[5]) + (rp[6] + rp[7]));
        int m = m0 + r, jj = jo & 15;
        if (jo < 16) { h2e[(size_t)m * 16 + jj] = acc; hl[r][jj] = acc; }
        else         e3[(size_t)m * 16 + jj] = acc + be[jj];
    }
    __syncthreads();
    {
        int q = tid & 7, ks2 = tid >> 3;
        float acc[8] = {};
        int k0 = ks2 * 16;
        for (int kk = 0; kk < 16; ++kk) {
            int k = k0 + kk;
            float b = wal[k * 8 + q];
#pragma unroll
            for (int r = 0; r < 8; ++r)
                acc[r] = fmaf(As[r * 1024 + k], b, acc[r]);
        }
#pragma unroll
        for (int r = 0; r < 8; ++r) red[(r * 8 + q) * 32 + ks2] = acc[r];
    }
    __syncthreads();
    if (tid < 64) {
        const float* rp = red + tid * 32;
        float acc = 0.f;
#pragma unroll
        for (int g = 0; g < 32; ++g) acc += rp[g];
        int r = tid >> 3, q = tid & 7;
        int m = m0 + r;
        if (q < 4) el2a[m * 4 + q] = acc;
        else       er2a[m * 4 + (q - 4)] = acc;
    }
    if (tid >= 64 && tid < 72) {
        int rr = tid - 64;
        float sl = 0.f, sr = 0.f;
        const float* hp = hl[rr];
        for (int d = 0; d < 16; ++d) { float v = hp[d]; sl = fmaf(v, al2e[d], sl); sr = fmaf(v, ar2e[d], sr); }
        el2e[m0 + rr] = sl;
        er2e[m0 + rr] = sr;
    }
}

// ---------- fused L2 softmax: 2a+walpha (idx<N*4) | e-head agg (rest) ----------
__global__ void k_sm_l2(const float* __restrict__ el2a, const float* __restrict__ er2a,
                        const float* __restrict__ el2e, const float* __restrict__ er2e,
                        const int* __restrict__ rowptr, const int* __restrict__ colidx,
                        const int* __restrict__ src,
                        const float* __restrict__ h2e,
                        float* __restrict__ walpha, float* __restrict__ e3, int N)
{
    int idx = blockIdx.x * blockDim.x + threadIdx.x;
    if (idx < N * 4) {
        int n = idx >> 2, hh = idx & 3;
        float ern = er2a[n * 4 + hh];
        int i0 = rowptr[n], i1 = rowptr[n + 1];
        float mx = -INFINITY;
        for (int i = i0; i < i1; ++i) {
            float v = el2a[src[colidx[i]] * 4 + hh] + ern;
            v = v >= 0.f ? v : 0.2f * v;
            mx = fmaxf(mx, v);
        }
        float s = 0.f;
        for (int i = i0; i < i1; ++i) {
            float v = el2a[src[colidx[i]] * 4 + hh] + ern;
            v = v >= 0.f ? v : 0.2f * v;
            s += expf(v - mx);
        }
        for (int i = i0; i < i1; ++i) {
            int e = colidx[i];
            int sn = src[e];
            float v = el2a[sn * 4 + hh] + ern;
            v = v >= 0.f ? v : 0.2f * v;
            float alpha = expf(v - mx) / s;
            atomicAdd(&walpha[sn * 4 + hh], alpha);
        }
        return;
    }
    int n = idx - N * 4;
    if (n >= N) return;
    float ern = er2e[n];
    int i0 = rowptr[n], i1 = rowptr[n + 1];
    float mx = -INFINITY;
    for (int i = i0; i < i1; ++i) {
        float v = el2e[src[colidx[i]]] + ern;
        v = v >= 0.f ? v : 0.2f * v;
        mx = fmaxf(mx, v);
    }
    float s = 0.f;
    for (int i = i0; i < i1; ++i) {
        float v = el2e[src[colidx[i]]] + ern;
        v = v >= 0.f ? v : 0.2f * v;
        s += expf(v - mx);
    }
    float4* e34 = (float4*)(e3 + (size_t)n * 16);
    float4 a0 = e34[0], a1 = e34[1], a2 = e34[2], a3 = e34[3];
    for (int i = i0; i < i1; ++i) {
        int e = colidx[i];
        int sn = src[e];
        float v = el2e[sn] + ern;
        v = v >= 0.f ? v : 0.2f * v;
        float al = expf(v - mx) / s;
        const float4* hp = (const float4*)(h2e + (size_t)sn * 16);
        float4 h0 = hp[0], h1 = hp[1], h2 = hp[2], h3 = hp[3];
        a0.x = fmaf(al, h0.x, a0.x); a0.y = fmaf(al, h0.y, a0.y); a0.z = fmaf(al, h0.z, a0.z); a0.w = fmaf(al, h0.w, a0.w);
        a1.x = fmaf(al, h1.x, a1.x); a1.y = fmaf(al, h1.y, a1.y); a1.z = fmaf(al, h1.z, a1.z); a1.w = fmaf(al, h1.w, a1.w);
        a2.x = fmaf(al, h2.x, a2.x); a2.y = fmaf(al, h2.y, a2.y); a2.z = fmaf(al, h2.z, a2.z); a2.w = fmaf(al, h2.w, a2.w);
        a3.x = fmaf(al, h3.x, a3.x); a3.y = fmaf(al, h3.y, a3.y); a3.z = fmaf(al, h3.z, a3.z); a3.w = fmaf(al, h3.w, a3.w);
    }
    e34[0] = a0; e34[1] = a1; e34[2] = a2; e34[3] = a3;
}

// ---------- attr partials (reconstructs a2 from acc+tf, bit-identical) ----------
__global__ __launch_bounds__(256) void k_pwa(const float* __restrict__ accb,
                                             const float* __restrict__ tf,
                                             const float* __restrict__ walpha,
                                             float* __restrict__ pwa)
{
    int b = blockIdx.x, t = threadIdx.x;
    float tf0 = tf[t], tf1 = tf[t + 256];
    float acc[5][2] = {};
    int n0 = b * 80, n1 = min(n0 + 80, NGR);
    for (int n = n0; n < n1; ++n) {
        const float* row = accb + (size_t)n * 512;
        const float* wa = walpha + n * 4;
        float w0 = wa[0], w1 = wa[1], w2 = wa[2], w3 = wa[3];
        float x0 = row[t] + tf0;       x0 = x0 >= 0.f ? x0 : 0.01f * x0;
        float x1 = row[t + 256] + tf1; x1 = x1 >= 0.f ? x1 : 0.01f * x1;
        acc[0][0] = fmaf(w0, x0, acc[0][0]); acc[0][1] = fmaf(w0, x1, acc[0][1]);
        acc[1][0] = fmaf(w1, x0, acc[1][0]); acc[1][1] = fmaf(w1, x1, acc[1][1]);
        acc[2][0] = fmaf(w2, x0, acc[2][0]); acc[2][1] = fmaf(w2, x1, acc[2][1]);
        acc[3][0] = fmaf(w3, x0, acc[3][0]); acc[3][1] = fmaf(w3, x1, acc[3][1]);
        acc[4][0] += x0; acc[4][1] += x1;
    }
#pragma unroll
    for (int q = 0; q < 5; ++q) {
        pwa[(size_t)b * 2560 + q * 512 + t] = acc[q][0];
        pwa[(size_t)b * 2560 + q * 512 + t + 256] = acc[q][1];
    }
}
__global__ void k_pwa_fin(const float* __restrict__ pwa, float* __restrict__ waw)
{
    int idx = blockIdx.x * blockDim.x + threadIdx.x;
    if (idx >= 2560) return;
    float s = 0.f;
    for (int b = 0; b < 125; ++b) s += pwa[(size_t)b * 2560 + idx];
    waw[idx] = s;
}

// ---------- attr GEMV (64 blocks) ----------
__global__ __launch_bounds__(256) void k_gemv3(const float* __restrict__ waw,
                                               const float* __restrict__ W2a, const float* __restrict__ R2a,
                                               const float* __restrict__ b2a,
                                               float* __restrict__ attrL)
{
    __shared__ float red[256];
    int b = blockIdx.x, t = threadIdx.x;
    int c = b * 16 + (t & 15);
    int hh = (b * 16) >> 8;
    int ks = (t >> 4) * 32;
    const float* wh = waw + hh * 512;
    const float* w4 = waw + 4 * 512;
    float s = 0.f;
#pragma unroll 8
    for (int k = ks; k < ks + 32; ++k) {
        s = fmaf(wh[k], W2a[(size_t)k * 1024 + c], s);
        s = fmaf(w4[k], R2a[(size_t)k * 1024 + c], s);
    }
    red[t] = s;
    __syncthreads();
    if (t < 16) {
        float v = 0.f;
#pragma unroll
        for (int g = 0; g < 16; ++g) v += red[t + g * 16];
        v = v / (float)NGR + b2a[b * 16 + t];
        attrL[b * 16 + t] = v >= 0.f ? v : 0.01f * v;
    }
}

// ---------- node_attr ----------
__global__ __launch_bounds__(256) void k_nattr2(const float* __restrict__ attrL,
                                                const float* __restrict__ Wo, const float* __restrict__ bo,
                                                float* __restrict__ out)
{
    __shared__ float al[64];
    int i = blockIdx.x, t = threadIdx.x;
    if (t < 64) al[t] = attrL[i * 64 + t];
    __syncthreads();
    float acc = 0.f;
#pragma unroll 8
    for (int d = 0; d < 64; ++d) acc = fmaf(al[d], Wo[d * 256 + t], acc);
    acc += bo[t];
    out[i * 256 + t] = acc;
    out[4096 + i * 256 + t] = acc;
}

// ---------- sampler stage 1: chunked softmax stats ----------
__global__ __launch_bounds__(256) void k_e3stats(const float* __restrict__ e3,
                                                 float* __restrict__ pm, float* __restrict__ ps)
{
    __shared__ float lds[4000];
    __shared__ float redm[16][16];
    __shared__ float reds[16][16];
    __shared__ float cm[16];
    int b = blockIdx.x, tid = threadIdx.x;
    int base = b * 250 * 16;
    for (int i = tid; i < 4000; i += 256) lds[i] = e3[base + i];
    __syncthreads();
    int c = tid & 15, g = tid >> 4;
    float mx = -INFINITY;
    for (int q = g; q < 250; q += 16) mx = fmaxf(mx, lds[q * 16 + c]);
    redm[c][g] = mx;
    __syncthreads();
    if (tid < 16) {
        float m = redm[tid][0];
        for (int q = 1; q < 16; ++q) m = fmaxf(m, redm[tid][q]);
        cm[tid] = m;
    }
    __syncthreads();
    float mb = cm[c];
    float s = 0.f;
    for (int q = g; q < 250; q += 16) s += expf(lds[q * 16 + c] - mb);
    reds[c][g] = s;
    __syncthreads();
    if (tid < 16) {
        float ss = 0.f;
        for (int q = 0; q < 16; ++q) ss += reds[tid][q];
        pm[b * 16 + tid] = cm[tid];
        ps[b * 16 + tid] = ss;
    }
}

// ---------- sampler stage 2: top-5 of g + p per (it,r,chunk) ----------
__global__ __launch_bounds__(256) void k_top5(const float* __restrict__ e3, const float* __restrict__ gum,
                                              const float* __restrict__ pm, const float* __restrict__ ps,
                                              float* __restrict__ probs,
                                              float* __restrict__ t5v, int* __restrict__ t5i)
{
    __shared__ float wv[4];
    __shared__ int wi[4];
    int chunk = blockIdx.x, y = blockIdx.y;
    int it = y >> 4, r = y & 15;
    int tid = threadIdx.x, lane = tid & 63, wid = tid >> 6;
    float M = -INFINITY;
    for (int b = 0; b < 40; ++b) M = fmaxf(M, pm[b * 16 + r]);
    float S = 0.f;
    for (int b = 0; b < 40; ++b) S += ps[b * 16 + r] * expf(pm[b * 16 + r] - M);
    float mxr = M, ssr = S;
    const float* g = gum + (size_t)y * NGR;
    int jb = chunk * 1250;
    float sv[5]; int si[5];
#pragma unroll
    for (int q = 0; q < 5; ++q) {
        int o = q * 256 + tid;
        float s = -INFINITY; int idx = 0x7FFFFFFF;
        if (o < 1250) {
            int j = jb + o;
            float p = expf(e3[(size_t)j * 16 + r] - mxr) / ssr;
            if (it == 0) probs[(size_t)r * NGR + j] = p;
            s = g[j] + p;
            idx = j;
        }
        sv[q] = s; si[q] = idx;
    }
    int outb = (y * 8 + chunk) * 5;
    for (int round = 0; round < 5; ++round) {
        float best = sv[0]; int bi = si[0];
#pragma unroll
        for (int q = 1; q < 5; ++q)
            if (sv[q] > best || (sv[q] == best && si[q] < bi)) { best = sv[q]; bi = si[q]; }
#pragma unroll
        for (int o = 32; o > 0; o >>= 1) {
            float ov = __shfl_xor(best, o, 64); int oi = __shfl_xor(bi, o, 64);
            if (ov > best || (ov == best && oi < bi)) { best = ov; bi = oi; }
        }
        if (lane == 0) { wv[wid] = best; wi[wid] = bi; }
        __syncthreads();
        float gbv = wv[0]; int gbi = wi[0];
#pragma unroll
        for (int w2 = 1; w2 < 4; ++w2) {
            float ov = wv[w2]; int oi = wi[w2];
            if (ov > gbv || (ov == gbv && oi < gbi)) { gbv = ov; gbi = oi; }
        }
        if (tid == 0) { t5v[outb + round] = gbv; t5i[outb + round] = gbi; }
#pragma unroll
        for (int q = 0; q < 5; ++q) if (si[q] == gbi) { sv[q] = -INFINITY; si[q] = 0x7FFFFFFF; }
        __syncthreads();
    }
}

// ---------- sampler stage 3: sequential exclusion ----------
__global__ void k_select(const int* __restrict__ tptr, const float* __restrict__ t5v,
                         const int* __restrict__ t5i, float* __restrict__ out_edges)
{
    int r = threadIdx.x;
    if (r >= 16) return;
    int s0 = *tptr, s1 = -1, s2 = -1, s3 = -1;
    out_edges[r * 5] = (float)s0;
    for (int it = 0; it < 4; ++it) {
        float best = -INFINITY; int bi = 0x7FFFFFFF;
        int base = (it * 16 + r) * 40;
        for (int c = 0; c < 40; ++c) {
            int idx = t5i[base + c];
            if (idx == s0 || idx == s1 || idx == s2 || idx == s3) continue;
            float v = t5v[base + c];
            if (v > best || (v == best && idx < bi)) { best = v; bi = idx; }
        }
        if (it == 0) s1 = bi; else if (it == 1) s2 = bi; else if (it == 2) s3 = bi;
        out_edges[r * 5 + it + 1] = (float)bi;
    }
}

extern "C" void kernel_launch(void* const* d_in, const int* in_sizes, int n_in,
                              void* d_out, int out_size, void* d_ws, size_t ws_size,
                              hipStream_t stream)
{
    const float* feat = (const float*)d_in[0];
    const int* src = (const int*)d_in[1];
    const int* dst = (const int*)d_in[2];
    const int* tptr = (const int*)d_in[3];
    const float* W1a = (const float*)d_in[4];  const float* al1a = (const float*)d_in[5];
    const float* ar1a = (const float*)d_in[6]; const float* R1a = (const float*)d_in[7];
    const float* b1a = (const float*)d_in[8];
    const float* W1e = (const float*)d_in[9];  const float* al1e = (const float*)d_in[10];
    const float* ar1e = (const float*)d_in[11]; const float* R1e = (const float*)d_in[12];
    const float* b1e = (const float*)d_in[13];
    const float* W2a = (const float*)d_in[14]; const float* al2a = (const float*)d_in[15];
    const float* ar2a = (const float*)d_in[16]; const float* R2a = (const float*)d_in[17];
    const float* b2a = (const float*)d_in[18];
    const float* W2e = (const float*)d_in[19]; const float* al2e = (const float*)d_in[20];
    const float* ar2e = (const float*)d_in[21]; const float* R2e = (const float*)d_in[22];
    const float* b2e = (const float*)d_in[23];
    const float* Wt = (const float*)d_in[24];  const float* bt = (const float*)d_in[25];
    const float* Wo = (const float*)d_in[26];  const float* bo = (const float*)d_in[27];
    const int E = in_sizes[1];
    const int N = NGR;

    float* ws = (float*)d_ws;
    float* regionA = ws;
    size_t off = (size_t)N * 1024;
    auto alloc = [&](size_t n) { float* p = ws + off; off += (n + 3) & ~(size_t)3; return p; };
    float* accb = alloc((size_t)N * 512);
    float* tf   = alloc(512);
    float* el1  = alloc((size_t)N * 8);
    float* er1  = alloc((size_t)N * 8);
    float* el2a = alloc((size_t)N * 4);
    float* er2a = alloc((size_t)N * 4);
    float* el2e = alloc(N);
    float* er2e = alloc(N);
    float* h2e  = alloc((size_t)N * 16);
    float* e3   = alloc((size_t)N * 16);
    float* ee1  = alloc((size_t)E * 8);
    float* packb = alloc(1024);
    float* gum   = alloc((size_t)4 * 16 * NGR);
    float* wal   = alloc(512 * 8);
    float* pwa   = alloc(125 * 2560);
    float* waw   = alloc(2560);
    float* attrL = alloc(1024);
    float* pm    = alloc(40 * 16);
    float* ps    = alloc(40 * 16);
    float* t5v   = alloc(64 * 40);
    int*   t5i   = (int*)alloc(64 * 40);
    unsigned short* feathi = (unsigned short*)alloc((size_t)10112 * 128);
    unsigned short* featlo = (unsigned short*)alloc((size_t)10112 * 128);
    unsigned short* WThi = (unsigned short*)alloc((size_t)1024 * 128);
    unsigned short* WTlo = (unsigned short*)alloc((size_t)1024 * 128);
    float* zstart = alloc((size_t)N * 6);
    float* walpha = zstart;
    int* deg    = (int*)(zstart + (size_t)N * 4);
    int* cursor = deg + N;
    int* rowptr = (int*)alloc(N + 1);
    int* colidx = (int*)alloc(E);

    float* out = (float*)d_out;
    float* out_edges = out + 8192;
    float* out_probs = out + 8272;

    dim3 blk(256);

    k_prep<<<5519, blk, 0, stream>>>(feat, tptr, Wt, bt, W1a, W1e, R1a, R1e, b1a, b1e,
                                     W2a, al2a, ar2a, feathi, featlo, WThi, WTlo,
                                     tf, gum, wal, packb, zstart);
    k_deg<<<(E + 255) / 256, blk, 0, stream>>>(dst, deg, E);
    k_scan<<<1, blk, 0, stream>>>(deg, rowptr, N);
    k_scatter<<<(E + 255) / 256, blk, 0, stream>>>(dst, rowptr, cursor, colidx, E);

    gemm_bf16x3<<<dim3(8, 79), blk, 0, stream>>>(feathi, featlo, WThi, WTlo, regionA, packb, N);
    k_el_er_l1<<<(N * 8 + 255) / 256, blk, 0, stream>>>(regionA, al1a, ar1a, al1e, ar1e, el1, er1, N);
    k_softmax_csr<<<(N * 8 + 255) / 256, blk, 0, stream>>>(el1, er1, rowptr, colidx, src, ee1, 8, 3, N * 8);
    k_agg_acc<<<(N * 128 + 255) / 256, blk, 0, stream>>>(ee1, rowptr, colidx, src,
                                                         regionA, accb, N * 128);

    k_node_linear<<<N / 8, blk, 0, stream>>>(accb, tf, W2e, R2e, b2e, wal, al2e, ar2e,
                                             h2e, e3, el2e, er2e, el2a, er2a);
    k_sm_l2<<<(N * 5 + 255) / 256, blk, 0, stream>>>(el2a, er2a, el2e, er2e,
                                                     rowptr, colidx, src, h2e, walpha, e3, N);

    k_pwa<<<125, blk, 0, stream>>>(accb, tf, walpha, pwa);
    k_pwa_fin<<<10, blk, 0, stream>>>(pwa, waw);
    k_gemv3<<<64, blk, 0, stream>>>(waw, W2a, R2a, b2a, attrL);
    k_nattr2<<<16, blk, 0, stream>>>(attrL, Wo, bo, out);

    k_e3stats<<<40, blk, 0, stream>>>(e3, pm, ps);
    k_top5<<<dim3(8, 64), blk, 0, stream>>>(e3, gum, pm, ps, out_probs, t5v, t5i);
    k_select<<<1, 64, 0, stream>>>(tptr, t5v, t5i, out_edges);
}

// Round 16
// 300.401 us; speedup vs baseline: 1.0742x; 1.0458x over previous
//
#include <hip/hip_runtime.h>
#include <hip/hip_bf16.h>

#define NGR 10000
typedef unsigned int u32;
typedef __attribute__((ext_vector_type(8))) short short8;
typedef __attribute__((ext_vector_type(4))) float f32x4;

// ---------- threefry2x32 (JAX-exact) ----------
__device__ __forceinline__ void threefry(u32 k0, u32 k1, u32 c0, u32 c1, u32& o0, u32& o1) {
    u32 ks2 = k0 ^ k1 ^ 0x1BD11BDAu;
    u32 x0 = c0 + k0, x1 = c1 + k1;
#define TF_R(r) { x0 += x1; x1 = (x1 << r) | (x1 >> (32 - r)); x1 ^= x0; }
    TF_R(13) TF_R(15) TF_R(26) TF_R(6)
    x0 += k1; x1 += ks2 + 1u;
    TF_R(17) TF_R(29) TF_R(16) TF_R(24)
    x0 += ks2; x1 += k0 + 2u;
    TF_R(13) TF_R(15) TF_R(26) TF_R(6)
    x0 += k0; x1 += k1 + 3u;
    TF_R(17) TF_R(29) TF_R(16) TF_R(24)
    x0 += k1; x1 += ks2 + 4u;
    TF_R(13) TF_R(15) TF_R(26) TF_R(6)
    x0 += ks2; x1 += k0 + 5u;
#undef TF_R
    o0 = x0; o1 = x1;
}

// ---------- CSR build ----------
__global__ void k_deg(const int* __restrict__ dst, int* __restrict__ deg, int E) {
    int i = blockIdx.x * blockDim.x + threadIdx.x;
    if (i < E) atomicAdd(&deg[dst[i]], 1);
}
__global__ void k_scan(const int* __restrict__ deg, int* __restrict__ rowptr, int n) {
    __shared__ int sums[256];
    __shared__ int excl[257];
    const int T = 256;
    int t = threadIdx.x;
    int per = (n + T - 1) / T;
    int lo = t * per, hi = min(lo + per, n);
    int s = 0;
    for (int i = lo; i < hi; ++i) s += deg[i];
    sums[t] = s;
    __syncthreads();
    if (t == 0) { int run = 0; for (int i = 0; i < T; ++i) { excl[i] = run; run += sums[i]; } excl[T] = run; }
    __syncthreads();
    int run = excl[t];
    for (int i = lo; i < hi; ++i) { rowptr[i] = run; run += deg[i]; }
    if (t == 0) rowptr[n] = excl[T];
}
__global__ void k_scatter(const int* __restrict__ dst, const int* __restrict__ rowptr,
                          int* __restrict__ cursor, int* __restrict__ colidx, int E) {
    int i = blockIdx.x * blockDim.x + threadIdx.x;
    if (i >= E) return;
    int d = dst[i];
    int pos = atomicAdd(&cursor[d], 1);
    colidx[rowptr[d] + pos] = i;
}

// ---------- mega-prep ----------
#define TINYF 1.17549435e-38f
__global__ __launch_bounds__(256) void k_prep(
    const float* __restrict__ feat, const int* __restrict__ tptr,
    const float* __restrict__ Wt, const float* __restrict__ bt,
    const float* __restrict__ W1a, const float* __restrict__ W1e,
    const float* __restrict__ R1a, const float* __restrict__ R1e,
    const float* __restrict__ b1a, const float* __restrict__ b1e,
    const float* __restrict__ W2a, const float* __restrict__ al2a, const float* __restrict__ ar2a,
    unsigned short* __restrict__ feathi, unsigned short* __restrict__ featlo,
    unsigned short* __restrict__ WThi, unsigned short* __restrict__ WTlo,
    float* __restrict__ tf, float* __restrict__ gum, float* __restrict__ wal,
    float* __restrict__ packb, float* __restrict__ zreg)
{
    __shared__ float sh[32 * 33];
    int b = blockIdx.x, tid = threadIdx.x;
    if (b < 2500) {
        int idx = b * 256 + tid;
        float4 v = ((const float4*)feat)[idx];
        ushort4 h, l;
        __hip_bfloat16 bb; float r;
        bb = __float2bfloat16(v.x); h.x = *(unsigned short*)&bb; r = v.x - __bfloat162float(bb);
        bb = __float2bfloat16(r);   l.x = *(unsigned short*)&bb;
        bb = __float2bfloat16(v.y); h.y = *(unsigned short*)&bb; r = v.y - __bfloat162float(bb);
        bb = __float2bfloat16(r);   l.y = *(unsigned short*)&bb;
        bb = __float2bfloat16(v.z); h.z = *(unsigned short*)&bb; r = v.z - __bfloat162float(bb);
        bb = __float2bfloat16(r);   l.z = *(unsigned short*)&bb;
        bb = __float2bfloat16(v.w); h.w = *(unsigned short*)&bb; r = v.w - __bfloat162float(bb);
        bb = __float2bfloat16(r);   l.w = *(unsigned short*)&bb;
        ((ushort4*)feathi)[idx] = h;
        ((ushort4*)featlo)[idx] = l;
        return;
    }
    b -= 2500;
    if (b < 256) {
        int bx = b >> 3, by = b & 7;
        int tx = tid & 31, ty = tid >> 5;
#pragma unroll
        for (int i = ty; i < 32; i += 8) {
            int k = by * 32 + i, c = bx * 32 + tx;
            float v;
            if (c < 256) v = W1a[k * 256 + c];
            else if (c < 512) v = W1e[k * 256 + c - 256];
            else if (c < 768) v = R1a[k * 256 + c - 512];
            else v = R1e[k * 256 + c - 768];
            sh[i * 33 + tx] = v;
        }
        __syncthreads();
#pragma unroll
        for (int i = ty; i < 32; i += 8) {
            float x = sh[tx * 33 + i];
            __hip_bfloat16 bh = __float2bfloat16(x);
            float r = x - __bfloat162float(bh);
            __hip_bfloat16 bl = __float2bfloat16(r);
            WThi[(size_t)(bx * 32 + i) * 256 + by * 32 + tx] = *(unsigned short*)&bh;
            WTlo[(size_t)(bx * 32 + i) * 256 + by * 32 + tx] = *(unsigned short*)&bl;
        }
        return;
    }
    b -= 256;
    if (b < 8) {
        float* frow = sh;
        float* red = sh + 256;
        int t = *tptr;
        frow[tid] = feat[t * 256 + tid];
        __syncthreads();
        int j = b * 64 + (tid & 63);
        int ks = (tid >> 6) * 64;
        float s = 0.f;
#pragma unroll 16
        for (int k = ks; k < ks + 64; ++k) s = fmaf(frow[k], Wt[(size_t)k * 512 + j], s);
        red[tid] = s;
        __syncthreads();
        if (tid < 64) {
            float v = red[tid] + red[tid + 64] + red[tid + 128] + red[tid + 192] + bt[j];
            tf[j] = v >= 0.f ? v : 0.01f * v;
        }
        return;
    }
    b -= 8;
    if (b < 2500) {
        int idx = b * 256 + tid;
        int it = idx / (16 * NGR);
        int f = idx - it * (16 * NGR);
        u32 fk0, fk1, o0, o1;
        threefry(0u, 42u, 0u, (u32)it, fk0, fk1);
        threefry(fk0, fk1, 0u, (u32)f, o0, o1);
        u32 bits = o0 ^ o1;
        float fl = __uint_as_float((bits >> 9) | 0x3F800000u) - 1.0f;
        float u = fmaxf(TINYF, fl + TINYF);
        gum[idx] = -logf(-logf(u));
        return;
    }
    b -= 2500;
    if (b < 128) {
        // wal, 128-block parallel: 4096 outputs x 8 k-slices of 32
        int o = b * 256 + tid;
        int outi = o >> 3, sl = o & 7;
        int k = outi >> 3, q = outi & 7, sel = q >> 2, hh = q & 3;
        const float* av = (sel ? ar2a : al2a) + hh * 256 + sl * 32;
        const float* wr = W2a + (size_t)k * 1024 + hh * 256 + sl * 32;
        float s = 0.f;
#pragma unroll 8
        for (int d = 0; d < 32; ++d) s = fmaf(wr[d], av[d], s);
        sh[tid] = s;
        __syncthreads();
        if ((tid & 7) == 0) {
            float v = ((sh[tid] + sh[tid + 1]) + (sh[tid + 2] + sh[tid + 3])) +
                      ((sh[tid + 4] + sh[tid + 5]) + (sh[tid + 6] + sh[tid + 7]));
            wal[outi] = v;
        }
        return;
    }
    b -= 128;
    if (b < 235) {
        int idx = b * 256 + tid;
        if (idx < NGR * 6) zreg[idx] = 0.f;
        return;
    }
    b -= 235;
    {
        int c = b * 256 + tid;
        packb[c] = (c < 512) ? 0.f : ((c < 768) ? b1a[c - 512] : b1e[c - 768]);
    }
}

// ---------- bf16x3 MFMA GEMM (f32-emulation), XCD-swizzled grid ----------
__global__ __launch_bounds__(256) void gemm_bf16x3(
    const unsigned short* __restrict__ Ahi, const unsigned short* __restrict__ Alo,
    const unsigned short* __restrict__ Bhi, const unsigned short* __restrict__ Blo,
    float* __restrict__ C, const float* __restrict__ bias, int M)
{
    constexpr int K = 256;
    __shared__ unsigned short AsH[2][128 * 32];
    __shared__ unsigned short AsL[2][128 * 32];
    __shared__ unsigned short BsH[2][128 * 32];
    __shared__ unsigned short BsL[2][128 * 32];
    const int tid = threadIdx.x;
    const int lane = tid & 63;
    const int w = tid >> 6, wr = w >> 1, wc = w & 1;
    // XCD-aware bijective swizzle (632 blocks, 632%8==0): lin -> (lin%8)*79 + lin/8
    int lin = blockIdx.y * 8 + blockIdx.x;
    int wg = (lin & 7) * 79 + (lin >> 3);
    const int bm = (wg >> 3) * 128, bn = (wg & 7) * 128;
    const int fr = lane & 15, fq = lane >> 4;
    const int srow = tid >> 2;
    const int sbyte = (tid & 3) * 16;
    f32x4 acc[4][4] = {};

    auto stage = [&](int b, int k0) {
        const char* pA[2] = {(const char*)Ahi, (const char*)Alo};
        const char* pB[2] = {(const char*)Bhi, (const char*)Blo};
        char* dA[2] = {(char*)AsH[b], (char*)AsL[b]};
        char* dB[2] = {(char*)BsH[b], (char*)BsL[b]};
#pragma unroll
        for (int q = 0; q < 2; ++q) {
            const char* ga0 = pA[q] + ((size_t)(bm + srow) * K + k0) * 2 + sbyte;
            const char* ga1 = pA[q] + ((size_t)(bm + 64 + srow) * K + k0) * 2 + sbyte;
            const char* gb0 = pB[q] + ((size_t)(bn + srow) * K + k0) * 2 + sbyte;
            const char* gb1 = pB[q] + ((size_t)(bn + 64 + srow) * K + k0) * 2 + sbyte;
            __builtin_amdgcn_global_load_lds((const __attribute__((address_space(1))) void*)ga0,
                (__attribute__((address_space(3))) void*)(dA[q] + tid * 16), 16, 0, 0);
            __builtin_amdgcn_global_load_lds((const __attribute__((address_space(1))) void*)ga1,
                (__attribute__((address_space(3))) void*)(dA[q] + 4096 + tid * 16), 16, 0, 0);
            __builtin_amdgcn_global_load_lds((const __attribute__((address_space(1))) void*)gb0,
                (__attribute__((address_space(3))) void*)(dB[q] + tid * 16), 16, 0, 0);
            __builtin_amdgcn_global_load_lds((const __attribute__((address_space(1))) void*)gb1,
                (__attribute__((address_space(3))) void*)(dB[q] + 4096 + tid * 16), 16, 0, 0);
        }
    };

    stage(0, 0);
    __syncthreads();
    int buf = 0;
    for (int t = 0; t < 8; ++t) {
        if (t < 7) stage(buf ^ 1, (t + 1) * 32);
        const char* ah = (const char*)AsH[buf];
        const char* al = (const char*)AsL[buf];
        const char* bh = (const char*)BsH[buf];
        const char* bl = (const char*)BsL[buf];
        short8 afh[4], afl[4], bfh[4], bfl[4];
#pragma unroll
        for (int m = 0; m < 4; ++m) {
            int o = (wr * 64 + m * 16 + fr) * 64 + fq * 16;
            afh[m] = *(const short8*)(ah + o);
            afl[m] = *(const short8*)(al + o);
        }
#pragma unroll
        for (int n = 0; n < 4; ++n) {
            int o = (wc * 64 + n * 16 + fr) * 64 + fq * 16;
            bfh[n] = *(const short8*)(bh + o);
            bfl[n] = *(const short8*)(bl + o);
        }
#pragma unroll
        for (int m = 0; m < 4; ++m)
#pragma unroll
            for (int n = 0; n < 4; ++n) {
                acc[m][n] = __builtin_amdgcn_mfma_f32_16x16x32_bf16(afl[m], bfh[n], acc[m][n], 0, 0, 0);
                acc[m][n] = __builtin_amdgcn_mfma_f32_16x16x32_bf16(afh[m], bfl[n], acc[m][n], 0, 0, 0);
                acc[m][n] = __builtin_amdgcn_mfma_f32_16x16x32_bf16(afh[m], bfh[n], acc[m][n], 0, 0, 0);
            }
        __syncthreads();
        buf ^= 1;
    }
#pragma unroll
    for (int m = 0; m < 4; ++m) {
#pragma unroll
        for (int i = 0; i < 4; ++i) {
            int row = bm + wr * 64 + m * 16 + fq * 4 + i;
            if (row >= M) continue;
#pragma unroll
            for (int n = 0; n < 4; ++n) {
                int col = bn + wc * 64 + n * 16 + fr;
                C[(size_t)row * 1024 + col] = acc[m][n][i] + bias[col];
            }
        }
    }
}

// ---------- L1 el/er for both heads ----------
__global__ void k_el_er_l1(const float* __restrict__ h,
                           const float* __restrict__ al1a, const float* __restrict__ ar1a,
                           const float* __restrict__ al1e, const float* __restrict__ ar1e,
                           float* __restrict__ el, float* __restrict__ er, int N)
{
    int idx = blockIdx.x * blockDim.x + threadIdx.x;
    if (idx >= N * 8) return;
    int n = idx >> 3, sub = idx & 7;
    int role = sub >> 2, hh = sub & 3;
    const float* hp = h + (size_t)n * 1024 + role * 256 + hh * 64;
    const float* alp = (role ? al1e : al1a) + hh * 64;
    const float* arp = (role ? ar1e : ar1a) + hh * 64;
    float sl = 0.f, sr = 0.f;
    for (int d = 0; d < 64; d += 4) {
        float4 v = *(const float4*)(hp + d);
        float4 a4 = *(const float4*)(alp + d);
        float4 r4 = *(const float4*)(arp + d);
        sl = fmaf(v.x, a4.x, sl); sl = fmaf(v.y, a4.y, sl); sl = fmaf(v.z, a4.z, sl); sl = fmaf(v.w, a4.w, sl);
        sr = fmaf(v.x, r4.x, sr); sr = fmaf(v.y, r4.y, sr); sr = fmaf(v.z, r4.z, sr); sr = fmaf(v.w, r4.w, sr);
    }
    el[n * 8 + sub] = sl;
    er[n * 8 + sub] = sr;
}

// ---------- CSR edge softmax (L1) ----------
__global__ void k_softmax_csr(const float* __restrict__ el, const float* __restrict__ er,
                              const int* __restrict__ rowptr, const int* __restrict__ colidx,
                              const int* __restrict__ src,
                              float* __restrict__ ee, int H, int hshift, int total)
{
    int idx = blockIdx.x * blockDim.x + threadIdx.x;
    if (idx >= total) return;
    int n = idx >> hshift, hh = idx & (H - 1);
    float ern = er[n * H + hh];
    int i0 = rowptr[n], i1 = rowptr[n + 1];
    float mx = -INFINITY;
    for (int i = i0; i < i1; ++i) {
        float v = el[src[colidx[i]] * H + hh] + ern;
        v = v >= 0.f ? v : 0.2f * v;
        mx = fmaxf(mx, v);
    }
    float s = 0.f;
    for (int i = i0; i < i1; ++i) {
        int e = colidx[i];
        float v = el[src[e] * H + hh] + ern;
        v = v >= 0.f ? v : 0.2f * v;
        float ex = expf(v - mx);
        ee[(size_t)e * H + hh] = ex;
        s += ex;
    }
    for (int i = i0; i < i1; ++i) {
        int e = colidx[i];
        ee[(size_t)e * H + hh] /= s;
    }
}

// ---------- L1 aggregation -> raw accumulator (4-way load batching, FMA order preserved) ----------
__global__ void k_agg_acc(const float* __restrict__ alpha,
                          const int* __restrict__ rowptr, const int* __restrict__ colidx,
                          const int* __restrict__ src,
                          const float* __restrict__ regionA,
                          float* __restrict__ accb, int total)
{
    int idx = blockIdx.x * blockDim.x + threadIdx.x;
    if (idx >= total) return;
    int n = idx >> 7, c4 = idx & 127;
    int hh = c4 >> 4;
    const float4* h4 = (const float4*)regionA;
    float4 acc = h4[(size_t)n * 256 + 128 + c4];
    int i = rowptr[n], i1 = rowptr[n + 1];
    for (; i + 3 < i1; i += 4) {
        int e0 = colidx[i], e1 = colidx[i + 1], e2 = colidx[i + 2], e3 = colidx[i + 3];
        int s0 = src[e0], s1 = src[e1], s2 = src[e2], s3 = src[e3];
        float a0 = alpha[(size_t)e0 * 8 + hh];
        float a1 = alpha[(size_t)e1 * 8 + hh];
        float a2 = alpha[(size_t)e2 * 8 + hh];
        float a3 = alpha[(size_t)e3 * 8 + hh];
        float4 h0 = h4[(size_t)s0 * 256 + c4];
        float4 h1 = h4[(size_t)s1 * 256 + c4];
        float4 h2 = h4[(size_t)s2 * 256 + c4];
        float4 h3 = h4[(size_t)s3 * 256 + c4];
        acc.x = fmaf(a0, h0.x, acc.x); acc.y = fmaf(a0, h0.y, acc.y);
        acc.z = fmaf(a0, h0.z, acc.z); acc.w = fmaf(a0, h0.w, acc.w);
        acc.x = fmaf(a1, h1.x, acc.x); acc.y = fmaf(a1, h1.y, acc.y);
        acc.z = fmaf(a1, h1.z, acc.z); acc.w = fmaf(a1, h1.w, acc.w);
        acc.x = fmaf(a2, h2.x, acc.x); acc.y = fmaf(a2, h2.y, acc.y);
        acc.z = fmaf(a2, h2.z, acc.z); acc.w = fmaf(a2, h2.w, acc.w);
        acc.x = fmaf(a3, h3.x, acc.x); acc.y = fmaf(a3, h3.y, acc.y);
        acc.z = fmaf(a3, h3.z, acc.z); acc.w = fmaf(a3, h3.w, acc.w);
    }
    for (; i < i1; ++i) {
        int e0 = colidx[i];
        float a0 = alpha[(size_t)e0 * 8 + hh];
        float4 h0 = h4[(size_t)src[e0] * 256 + c4];
        acc.x = fmaf(a0, h0.x, acc.x); acc.y = fmaf(a0, h0.y, acc.y);
        acc.z = fmaf(a0, h0.z, acc.z); acc.w = fmaf(a0, h0.w, acc.w);
    }
    ((float4*)accb)[(size_t)n * 128 + c4] = acc;
}

// ---------- node-linear v2: reconstructs a2/e2 from acc+tf (bit-identical) ----------
__global__ __launch_bounds__(256) void k_node_linear(
    const float* __restrict__ accb, const float* __restrict__ tf,
    const float* __restrict__ We, const float* __restrict__ Re, const float* __restrict__ be,
    const float* __restrict__ wal,
    const float* __restrict__ al2e, const float* __restrict__ ar2e,
    float* __restrict__ h2e, float* __restrict__ e3,
    float* __restrict__ el2e, float* __restrict__ er2e,
    float* __restrict__ el2a, float* __restrict__ er2a)
{
    __shared__ float As[8 * 1024];
    __shared__ float red[2048];
    __shared__ float hl[8][16];
    int tid = threadIdx.x;
    int m0 = blockIdx.x * 8;
    for (int i = tid; i < 8 * 128; i += 256) {
        int row = i >> 7, c = (i & 127) << 2;
        float4 a = *(const float4*)(accb + (size_t)(m0 + row) * 512 + c);
        int cc = (c + 256) & 511;
        float4 ta = *(const float4*)(tf + c);
        float4 te = *(const float4*)(tf + cc);
        float4 xa, xe;
        xa.x = a.x + ta.x; xa.y = a.y + ta.y; xa.z = a.z + ta.z; xa.w = a.w + ta.w;
        xe.x = a.x + te.x; xe.y = a.y + te.y; xe.z = a.z + te.z; xe.w = a.w + te.w;
        xa.x = xa.x >= 0.f ? xa.x : 0.01f * xa.x;
        xa.y = xa.y >= 0.f ? xa.y : 0.01f * xa.y;
        xa.z = xa.z >= 0.f ? xa.z : 0.01f * xa.z;
        xa.w = xa.w >= 0.f ? xa.w : 0.01f * xa.w;
        xe.x = xe.x >= 0.f ? xe.x : 0.01f * xe.x;
        xe.y = xe.y >= 0.f ? xe.y : 0.01f * xe.y;
        xe.z = xe.z >= 0.f ? xe.z : 0.01f * xe.z;
        xe.w = xe.w >= 0.f ? xe.w : 0.01f * xe.w;
        *(float4*)(As + row * 1024 + c) = xa;
        *(float4*)(As + row * 1024 + 512 + cc) = xe;
    }
    __syncthreads();
    {
        int j = tid & 31, ks = tid >> 5;
        const float* B = (j < 16) ? We : Re;
        int jj = j & 15;
        float acc[8] = {};
        int k0 = ks * 64;
        for (int kk = 0; kk < 64; kk += 4) {
            int k = k0 + kk;
            float b0 = B[(k + 0) * 16 + jj];
            float b1 = B[(k + 1) * 16 + jj];
            float b2 = B[(k + 2) * 16 + jj];
            float b3 = B[(k + 3) * 16 + jj];
#pragma unroll
            for (int r = 0; r < 8; ++r) {
                float4 a = *(const float4*)(As + r * 1024 + 512 + k);
                acc[r] = fmaf(a.x, b0, acc[r]);
                acc[r] = fmaf(a.y, b1, acc[r]);
                acc[r] = fmaf(a.z, b2, acc[r]);
                acc[r] = fmaf(a.w, b3, acc[r]);
            }
        }
#pragma unroll
        for (int r = 0; r < 8; ++r) red[(r * 32 + j) * 8 + ks] = acc[r];
    }
    __syncthreads();
    {
        int r = tid >> 5, jo = tid & 31;
        const float* rp = red + (r * 32 + jo) * 8;
        float acc = ((rp[0] + rp[1]) + (rp[2] + rp[3])) + ((rp[4] + rp[5]) + (rp[6] + rp[7]));
        int m = m0 + r, jj = jo & 15;
        if (jo < 16) { h2e[(size_t)m * 16 + jj] = acc; hl[r][jj] = acc; }
        else         e3[(size_t)m * 16 + jj] = acc + be[jj];
    }
    __syncthreads();
    {
        int q = tid & 7, ks2 = tid >> 3;
        float acc[8] = {};
        int k0 = ks2 * 16;
        for (int kk = 0; kk < 16; ++kk) {
            int k = k0 + kk;
            float b = wal[k * 8 + q];
#pragma unroll
            for (int r = 0; r < 8; ++r)
                acc[r] = fmaf(As[r * 1024 + k], b, acc[r]);
        }
#pragma unroll
        for (int r = 0; r < 8; ++r) red[(r * 8 + q) * 32 + ks2] = acc[r];
    }
    __syncthreads();
    if (tid < 64) {
        const float* rp = red + tid * 32;
        float acc = 0.f;
#pragma unroll
        for (int g = 0; g < 32; ++g) acc += rp[g];
        int r = tid >> 3, q = tid & 7;
        int m = m0 + r;
        if (q < 4) el2a[m * 4 + q] = acc;
        else       er2a[m * 4 + (q - 4)] = acc;
    }
    if (tid >= 64 && tid < 72) {
        int rr = tid - 64;
        float sl = 0.f, sr = 0.f;
        const float* hp = hl[rr];
        for (int d = 0; d < 16; ++d) { float v = hp[d]; sl = fmaf(v, al2e[d], sl); sr = fmaf(v, ar2e[d], sr); }
        el2e[m0 + rr] = sl;
        er2e[m0 + rr] = sr;
    }
}

// ---------- fused L2 softmax: 2a+walpha (idx<N*4) | e-head agg (rest) ----------
__global__ void k_sm_l2(const float* __restrict__ el2a, const float* __restrict__ er2a,
                        const float* __restrict__ el2e, const float* __restrict__ er2e,
                        const int* __restrict__ rowptr, const int* __restrict__ colidx,
                        const int* __restrict__ src,
                        const float* __restrict__ h2e,
                        float* __restrict__ walpha, float* __restrict__ e3, int N)
{
    int idx = blockIdx.x * blockDim.x + threadIdx.x;
    if (idx < N * 4) {
        int n = idx >> 2, hh = idx & 3;
        float ern = er2a[n * 4 + hh];
        int i0 = rowptr[n], i1 = rowptr[n + 1];
        float mx = -INFINITY;
        for (int i = i0; i < i1; ++i) {
            float v = el2a[src[colidx[i]] * 4 + hh] + ern;
            v = v >= 0.f ? v : 0.2f * v;
            mx = fmaxf(mx, v);
        }
        float s = 0.f;
        for (int i = i0; i < i1; ++i) {
            float v = el2a[src[colidx[i]] * 4 + hh] + ern;
            v = v >= 0.f ? v : 0.2f * v;
            s += expf(v - mx);
        }
        for (int i = i0; i < i1; ++i) {
            int e = colidx[i];
            int sn = src[e];
            float v = el2a[sn * 4 + hh] + ern;
            v = v >= 0.f ? v : 0.2f * v;
            float alpha = expf(v - mx) / s;
            atomicAdd(&walpha[sn * 4 + hh], alpha);
        }
        return;
    }
    int n = idx - N * 4;
    if (n >= N) return;
    float ern = er2e[n];
    int i0 = rowptr[n], i1 = rowptr[n + 1];
    float mx = -INFINITY;
    for (int i = i0; i < i1; ++i) {
        float v = el2e[src[colidx[i]]] + ern;
        v = v >= 0.f ? v : 0.2f * v;
        mx = fmaxf(mx, v);
    }
    float s = 0.f;
    for (int i = i0; i < i1; ++i) {
        float v = el2e[src[colidx[i]]] + ern;
        v = v >= 0.f ? v : 0.2f * v;
        s += expf(v - mx);
    }
    float4* e34 = (float4*)(e3 + (size_t)n * 16);
    float4 a0 = e34[0], a1 = e34[1], a2 = e34[2], a3 = e34[3];
    for (int i = i0; i < i1; ++i) {
        int e = colidx[i];
        int sn = src[e];
        float v = el2e[sn] + ern;
        v = v >= 0.f ? v : 0.2f * v;
        float al = expf(v - mx) / s;
        const float4* hp = (const float4*)(h2e + (size_t)sn * 16);
        float4 h0 = hp[0], h1 = hp[1], h2 = hp[2], h3 = hp[3];
        a0.x = fmaf(al, h0.x, a0.x); a0.y = fmaf(al, h0.y, a0.y); a0.z = fmaf(al, h0.z, a0.z); a0.w = fmaf(al, h0.w, a0.w);
        a1.x = fmaf(al, h1.x, a1.x); a1.y = fmaf(al, h1.y, a1.y); a1.z = fmaf(al, h1.z, a1.z); a1.w = fmaf(al, h1.w, a1.w);
        a2.x = fmaf(al, h2.x, a2.x); a2.y = fmaf(al, h2.y, a2.y); a2.z = fmaf(al, h2.z, a2.z); a2.w = fmaf(al, h2.w, a2.w);
        a3.x = fmaf(al, h3.x, a3.x); a3.y = fmaf(al, h3.y, a3.y); a3.z = fmaf(al, h3.z, a3.z); a3.w = fmaf(al, h3.w, a3.w);
    }
    e34[0] = a0; e34[1] = a1; e34[2] = a2; e34[3] = a3;
}

// ---------- attr partials (reconstructs a2 from acc+tf) ----------
__global__ __launch_bounds__(256) void k_pwa(const float* __restrict__ accb,
                                             const float* __restrict__ tf,
                                             const float* __restrict__ walpha,
                                             float* __restrict__ pwa)
{
    int b = blockIdx.x, t = threadIdx.x;
    float tf0 = tf[t], tf1 = tf[t + 256];
    float acc[5][2] = {};
    int n0 = b * 80, n1 = min(n0 + 80, NGR);
    for (int n = n0; n < n1; ++n) {
        const float* row = accb + (size_t)n * 512;
        const float* wa = walpha + n * 4;
        float w0 = wa[0], w1 = wa[1], w2 = wa[2], w3 = wa[3];
        float x0 = row[t] + tf0;       x0 = x0 >= 0.f ? x0 : 0.01f * x0;
        float x1 = row[t + 256] + tf1; x1 = x1 >= 0.f ? x1 : 0.01f * x1;
        acc[0][0] = fmaf(w0, x0, acc[0][0]); acc[0][1] = fmaf(w0, x1, acc[0][1]);
        acc[1][0] = fmaf(w1, x0, acc[1][0]); acc[1][1] = fmaf(w1, x1, acc[1][1]);
        acc[2][0] = fmaf(w2, x0, acc[2][0]); acc[2][1] = fmaf(w2, x1, acc[2][1]);
        acc[3][0] = fmaf(w3, x0, acc[3][0]); acc[3][1] = fmaf(w3, x1, acc[3][1]);
        acc[4][0] += x0; acc[4][1] += x1;
    }
#pragma unroll
    for (int q = 0; q < 5; ++q) {
        pwa[(size_t)b * 2560 + q * 512 + t] = acc[q][0];
        pwa[(size_t)b * 2560 + q * 512 + t + 256] = acc[q][1];
    }
}
__global__ void k_pwa_fin(const float* __restrict__ pwa, float* __restrict__ waw)
{
    int idx = blockIdx.x * blockDim.x + threadIdx.x;
    if (idx >= 2560) return;
    float s = 0.f;
    for (int b = 0; b < 125; ++b) s += pwa[(size_t)b * 2560 + idx];
    waw[idx] = s;
}

// ---------- attr GEMV (64 blocks) ----------
__global__ __launch_bounds__(256) void k_gemv3(const float* __restrict__ waw,
                                               const float* __restrict__ W2a, const float* __restrict__ R2a,
                                               const float* __restrict__ b2a,
                                               float* __restrict__ attrL)
{
    __shared__ float red[256];
    int b = blockIdx.x, t = threadIdx.x;
    int c = b * 16 + (t & 15);
    int hh = (b * 16) >> 8;
    int ks = (t >> 4) * 32;
    const float* wh = waw + hh * 512;
    const float* w4 = waw + 4 * 512;
    float s = 0.f;
#pragma unroll 8
    for (int k = ks; k < ks + 32; ++k) {
        s = fmaf(wh[k], W2a[(size_t)k * 1024 + c], s);
        s = fmaf(w4[k], R2a[(size_t)k * 1024 + c], s);
    }
    red[t] = s;
    __syncthreads();
    if (t < 16) {
        float v = 0.f;
#pragma unroll
        for (int g = 0; g < 16; ++g) v += red[t + g * 16];
        v = v / (float)NGR + b2a[b * 16 + t];
        attrL[b * 16 + t] = v >= 0.f ? v : 0.01f * v;
    }
}

// ---------- node_attr ----------
__global__ __launch_bounds__(256) void k_nattr2(const float* __restrict__ attrL,
                                                const float* __restrict__ Wo, const float* __restrict__ bo,
                                                float* __restrict__ out)
{
    __shared__ float al[64];
    int i = blockIdx.x, t = threadIdx.x;
    if (t < 64) al[t] = attrL[i * 64 + t];
    __syncthreads();
    float acc = 0.f;
#pragma unroll 8
    for (int d = 0; d < 64; ++d) acc = fmaf(al[d], Wo[d * 256 + t], acc);
    acc += bo[t];
    out[i * 256 + t] = acc;
    out[4096 + i * 256 + t] = acc;
}

// ---------- sampler stage 1: chunked softmax stats ----------
__global__ __launch_bounds__(256) void k_e3stats(const float* __restrict__ e3,
                                                 float* __restrict__ pm, float* __restrict__ ps)
{
    __shared__ float lds[4000];
    __shared__ float redm[16][16];
    __shared__ float reds[16][16];
    __shared__ float cm[16];
    int b = blockIdx.x, tid = threadIdx.x;
    int base = b * 250 * 16;
    for (int i = tid; i < 4000; i += 256) lds[i] = e3[base + i];
    __syncthreads();
    int c = tid & 15, g = tid >> 4;
    float mx = -INFINITY;
    for (int q = g; q < 250; q += 16) mx = fmaxf(mx, lds[q * 16 + c]);
    redm[c][g] = mx;
    __syncthreads();
    if (tid < 16) {
        float m = redm[tid][0];
        for (int q = 1; q < 16; ++q) m = fmaxf(m, redm[tid][q]);
        cm[tid] = m;
    }
    __syncthreads();
    float mb = cm[c];
    float s = 0.f;
    for (int q = g; q < 250; q += 16) s += expf(lds[q * 16 + c] - mb);
    reds[c][g] = s;
    __syncthreads();
    if (tid < 16) {
        float ss = 0.f;
        for (int q = 0; q < 16; ++q) ss += reds[tid][q];
        pm[b * 16 + tid] = cm[tid];
        ps[b * 16 + tid] = ss;
    }
}

// ---------- sampler stage 2: top-5 of g + p per (it,r,chunk) ----------
__global__ __launch_bounds__(256) void k_top5(const float* __restrict__ e3, const float* __restrict__ gum,
                                              const float* __restrict__ pm, const float* __restrict__ ps,
                                              float* __restrict__ probs,
                                              float* __restrict__ t5v, int* __restrict__ t5i)
{
    __shared__ float wv[4];
    __shared__ int wi[4];
    int chunk = blockIdx.x, y = blockIdx.y;
    int it = y >> 4, r = y & 15;
    int tid = threadIdx.x, lane = tid & 63, wid = tid >> 6;
    float M = -INFINITY;
    for (int b = 0; b < 40; ++b) M = fmaxf(M, pm[b * 16 + r]);
    float S = 0.f;
    for (int b = 0; b < 40; ++b) S += ps[b * 16 + r] * expf(pm[b * 16 + r] - M);
    float mxr = M, ssr = S;
    const float* g = gum + (size_t)y * NGR;
    int jb = chunk * 1250;
    float sv[5]; int si[5];
#pragma unroll
    for (int q = 0; q < 5; ++q) {
        int o = q * 256 + tid;
        float s = -INFINITY; int idx = 0x7FFFFFFF;
        if (o < 1250) {
            int j = jb + o;
            float p = expf(e3[(size_t)j * 16 + r] - mxr) / ssr;
            if (it == 0) probs[(size_t)r * NGR + j] = p;
            s = g[j] + p;
            idx = j;
        }
        sv[q] = s; si[q] = idx;
    }
    int outb = (y * 8 + chunk) * 5;
    for (int round = 0; round < 5; ++round) {
        float best = sv[0]; int bi = si[0];
#pragma unroll
        for (int q = 1; q < 5; ++q)
            if (sv[q] > best || (sv[q] == best && si[q] < bi)) { best = sv[q]; bi = si[q]; }
#pragma unroll
        for (int o = 32; o > 0; o >>= 1) {
            float ov = __shfl_xor(best, o, 64); int oi = __shfl_xor(bi, o, 64);
            if (ov > best || (ov == best && oi < bi)) { best = ov; bi = oi; }
        }
        if (lane == 0) { wv[wid] = best; wi[wid] = bi; }
        __syncthreads();
        float gbv = wv[0]; int gbi = wi[0];
#pragma unroll
        for (int w2 = 1; w2 < 4; ++w2) {
            float ov = wv[w2]; int oi = wi[w2];
            if (ov > gbv || (ov == gbv && oi < gbi)) { gbv = ov; gbi = oi; }
        }
        if (tid == 0) { t5v[outb + round] = gbv; t5i[outb + round] = gbi; }
#pragma unroll
        for (int q = 0; q < 5; ++q) if (si[q] == gbi) { sv[q] = -INFINITY; si[q] = 0x7FFFFFFF; }
        __syncthreads();
    }
}

// ---------- sampler stage 3: sequential exclusion ----------
__global__ void k_select(const int* __restrict__ tptr, const float* __restrict__ t5v,
                         const int* __restrict__ t5i, float* __restrict__ out_edges)
{
    int r = threadIdx.x;
    if (r >= 16) return;
    int s0 = *tptr, s1 = -1, s2 = -1, s3 = -1;
    out_edges[r * 5] = (float)s0;
    for (int it = 0; it < 4; ++it) {
        float best = -INFINITY; int bi = 0x7FFFFFFF;
        int base = (it * 16 + r) * 40;
        for (int c = 0; c < 40; ++c) {
            int idx = t5i[base + c];
            if (idx == s0 || idx == s1 || idx == s2 || idx == s3) continue;
            float v = t5v[base + c];
            if (v > best || (v == best && idx < bi)) { best = v; bi = idx; }
        }
        if (it == 0) s1 = bi; else if (it == 1) s2 = bi; else if (it == 2) s3 = bi;
        out_edges[r * 5 + it + 1] = (float)bi;
    }
}

extern "C" void kernel_launch(void* const* d_in, const int* in_sizes, int n_in,
                              void* d_out, int out_size, void* d_ws, size_t ws_size,
                              hipStream_t stream)
{
    const float* feat = (const float*)d_in[0];
    const int* src = (const int*)d_in[1];
    const int* dst = (const int*)d_in[2];
    const int* tptr = (const int*)d_in[3];
    const float* W1a = (const float*)d_in[4];  const float* al1a = (const float*)d_in[5];
    const float* ar1a = (const float*)d_in[6]; const float* R1a = (const float*)d_in[7];
    const float* b1a = (const float*)d_in[8];
    const float* W1e = (const float*)d_in[9];  const float* al1e = (const float*)d_in[10];
    const float* ar1e = (const float*)d_in[11]; const float* R1e = (const float*)d_in[12];
    const float* b1e = (const float*)d_in[13];
    const float* W2a = (const float*)d_in[14]; const float* al2a = (const float*)d_in[15];
    const float* ar2a = (const float*)d_in[16]; const float* R2a = (const float*)d_in[17];
    const float* b2a = (const float*)d_in[18];
    const float* W2e = (const float*)d_in[19]; const float* al2e = (const float*)d_in[20];
    const float* ar2e = (const float*)d_in[21]; const float* R2e = (const float*)d_in[22];
    const float* b2e = (const float*)d_in[23];
    const float* Wt = (const float*)d_in[24];  const float* bt = (const float*)d_in[25];
    const float* Wo = (const float*)d_in[26];  const float* bo = (const float*)d_in[27];
    const int E = in_sizes[1];
    const int N = NGR;

    float* ws = (float*)d_ws;
    float* regionA = ws;
    size_t off = (size_t)N * 1024;
    auto alloc = [&](size_t n) { float* p = ws + off; off += (n + 3) & ~(size_t)3; return p; };
    float* accb = alloc((size_t)N * 512);
    float* tf   = alloc(512);
    float* el1  = alloc((size_t)N * 8);
    float* er1  = alloc((size_t)N * 8);
    float* el2a = alloc((size_t)N * 4);
    float* er2a = alloc((size_t)N * 4);
    float* el2e = alloc(N);
    float* er2e = alloc(N);
    float* h2e  = alloc((size_t)N * 16);
    float* e3   = alloc((size_t)N * 16);
    float* ee1  = alloc((size_t)E * 8);
    float* packb = alloc(1024);
    float* gum   = alloc((size_t)4 * 16 * NGR);
    float* wal   = alloc(512 * 8);
    float* pwa   = alloc(125 * 2560);
    float* waw   = alloc(2560);
    float* attrL = alloc(1024);
    float* pm    = alloc(40 * 16);
    float* ps    = alloc(40 * 16);
    float* t5v   = alloc(64 * 40);
    int*   t5i   = (int*)alloc(64 * 40);
    unsigned short* feathi = (unsigned short*)alloc((size_t)10112 * 128);
    unsigned short* featlo = (unsigned short*)alloc((size_t)10112 * 128);
    unsigned short* WThi = (unsigned short*)alloc((size_t)1024 * 128);
    unsigned short* WTlo = (unsigned short*)alloc((size_t)1024 * 128);
    float* zstart = alloc((size_t)N * 6);
    float* walpha = zstart;
    int* deg    = (int*)(zstart + (size_t)N * 4);
    int* cursor = deg + N;
    int* rowptr = (int*)alloc(N + 1);
    int* colidx = (int*)alloc(E);

    float* out = (float*)d_out;
    float* out_edges = out + 8192;
    float* out_probs = out + 8272;

    dim3 blk(256);

    k_prep<<<5631, blk, 0, stream>>>(feat, tptr, Wt, bt, W1a, W1e, R1a, R1e, b1a, b1e,
                                     W2a, al2a, ar2a, feathi, featlo, WThi, WTlo,
                                     tf, gum, wal, packb, zstart);
    k_deg<<<(E + 255) / 256, blk, 0, stream>>>(dst, deg, E);
    k_scan<<<1, blk, 0, stream>>>(deg, rowptr, N);
    k_scatter<<<(E + 255) / 256, blk, 0, stream>>>(dst, rowptr, cursor, colidx, E);

    gemm_bf16x3<<<dim3(8, 79), blk, 0, stream>>>(feathi, featlo, WThi, WTlo, regionA, packb, N);
    k_el_er_l1<<<(N * 8 + 255) / 256, blk, 0, stream>>>(regionA, al1a, ar1a, al1e, ar1e, el1, er1, N);
    k_softmax_csr<<<(N * 8 + 255) / 256, blk, 0, stream>>>(el1, er1, rowptr, colidx, src, ee1, 8, 3, N * 8);
    k_agg_acc<<<(N * 128 + 255) / 256, blk, 0, stream>>>(ee1, rowptr, colidx, src,
                                                         regionA, accb, N * 128);

    k_node_linear<<<N / 8, blk, 0, stream>>>(accb, tf, W2e, R2e, b2e, wal, al2e, ar2e,
                                             h2e, e3, el2e, er2e, el2a, er2a);
    k_sm_l2<<<(N * 5 + 255) / 256, blk, 0, stream>>>(el2a, er2a, el2e, er2e,
                                                     rowptr, colidx, src, h2e, walpha, e3, N);

    k_pwa<<<125, blk, 0, stream>>>(accb, tf, walpha, pwa);
    k_pwa_fin<<<10, blk, 0, stream>>>(pwa, waw);
    k_gemv3<<<64, blk, 0, stream>>>(waw, W2a, R2a, b2a, attrL);
    k_nattr2<<<16, blk, 0, stream>>>(attrL, Wo, bo, out);

    k_e3stats<<<40, blk, 0, stream>>>(e3, pm, ps);
    k_top5<<<dim3(8, 64), blk, 0, stream>>>(e3, gum, pm, ps, out_probs, t5v, t5i);
    k_select<<<1, 64, 0, stream>>>(tptr, t5v, t5i, out_edges);
}

// Round 17
// 289.938 us; speedup vs baseline: 1.1130x; 1.0361x over previous
//
#include <hip/hip_runtime.h>
#include <hip/hip_bf16.h>

#define NGR 10000
typedef unsigned int u32;
typedef __attribute__((ext_vector_type(8))) short short8;
typedef __attribute__((ext_vector_type(4))) float f32x4;

// ---------- threefry2x32 (JAX-exact) ----------
__device__ __forceinline__ void threefry(u32 k0, u32 k1, u32 c0, u32 c1, u32& o0, u32& o1) {
    u32 ks2 = k0 ^ k1 ^ 0x1BD11BDAu;
    u32 x0 = c0 + k0, x1 = c1 + k1;
#define TF_R(r) { x0 += x1; x1 = (x1 << r) | (x1 >> (32 - r)); x1 ^= x0; }
    TF_R(13) TF_R(15) TF_R(26) TF_R(6)
    x0 += k1; x1 += ks2 + 1u;
    TF_R(17) TF_R(29) TF_R(16) TF_R(24)
    x0 += ks2; x1 += k0 + 2u;
    TF_R(13) TF_R(15) TF_R(26) TF_R(6)
    x0 += k0; x1 += k1 + 3u;
    TF_R(17) TF_R(29) TF_R(16) TF_R(24)
    x0 += k1; x1 += ks2 + 4u;
    TF_R(13) TF_R(15) TF_R(26) TF_R(6)
    x0 += ks2; x1 += k0 + 5u;
#undef TF_R
    o0 = x0; o1 = x1;
}

// ---------- CSR build ----------
__global__ void k_deg(const int* __restrict__ dst, int* __restrict__ deg, int E) {
    int i = blockIdx.x * blockDim.x + threadIdx.x;
    if (i < E) atomicAdd(&deg[dst[i]], 1);
}
__global__ void k_scan(const int* __restrict__ deg, int* __restrict__ rowptr, int n) {
    __shared__ int sums[256];
    __shared__ int excl[257];
    const int T = 256;
    int t = threadIdx.x;
    int per = (n + T - 1) / T;
    int lo = t * per, hi = min(lo + per, n);
    int s = 0;
    for (int i = lo; i < hi; ++i) s += deg[i];
    sums[t] = s;
    __syncthreads();
    if (t == 0) { int run = 0; for (int i = 0; i < T; ++i) { excl[i] = run; run += sums[i]; } excl[T] = run; }
    __syncthreads();
    int run = excl[t];
    for (int i = lo; i < hi; ++i) { rowptr[i] = run; run += deg[i]; }
    if (t == 0) rowptr[n] = excl[T];
}
__global__ void k_scatter(const int* __restrict__ dst, const int* __restrict__ rowptr,
                          int* __restrict__ cursor, int* __restrict__ colidx, int E) {
    int i = blockIdx.x * blockDim.x + threadIdx.x;
    if (i >= E) return;
    int d = dst[i];
    int pos = atomicAdd(&cursor[d], 1);
    colidx[rowptr[d] + pos] = i;
}

// ---------- mega-prep ----------
#define TINYF 1.17549435e-38f
__global__ __launch_bounds__(256) void k_prep(
    const float* __restrict__ feat, const int* __restrict__ tptr,
    const float* __restrict__ Wt, const float* __restrict__ bt,
    const float* __restrict__ W1a, const float* __restrict__ W1e,
    const float* __restrict__ R1a, const float* __restrict__ R1e,
    const float* __restrict__ b1a, const float* __restrict__ b1e,
    const float* __restrict__ W2a, const float* __restrict__ al2a, const float* __restrict__ ar2a,
    unsigned short* __restrict__ feathi, unsigned short* __restrict__ featlo,
    unsigned short* __restrict__ WThi, unsigned short* __restrict__ WTlo,
    float* __restrict__ tf, float* __restrict__ gum, float* __restrict__ wal,
    float* __restrict__ packb, float* __restrict__ zreg)
{
    __shared__ float sh[32 * 33];
    int b = blockIdx.x, tid = threadIdx.x;
    if (b < 2500) {
        int idx = b * 256 + tid;
        float4 v = ((const float4*)feat)[idx];
        ushort4 h, l;
        __hip_bfloat16 bb; float r;
        bb = __float2bfloat16(v.x); h.x = *(unsigned short*)&bb; r = v.x - __bfloat162float(bb);
        bb = __float2bfloat16(r);   l.x = *(unsigned short*)&bb;
        bb = __float2bfloat16(v.y); h.y = *(unsigned short*)&bb; r = v.y - __bfloat162float(bb);
        bb = __float2bfloat16(r);   l.y = *(unsigned short*)&bb;
        bb = __float2bfloat16(v.z); h.z = *(unsigned short*)&bb; r = v.z - __bfloat162float(bb);
        bb = __float2bfloat16(r);   l.z = *(unsigned short*)&bb;
        bb = __float2bfloat16(v.w); h.w = *(unsigned short*)&bb; r = v.w - __bfloat162float(bb);
        bb = __float2bfloat16(r);   l.w = *(unsigned short*)&bb;
        ((ushort4*)feathi)[idx] = h;
        ((ushort4*)featlo)[idx] = l;
        return;
    }
    b -= 2500;
    if (b < 256) {
        int bx = b >> 3, by = b & 7;
        int tx = tid & 31, ty = tid >> 5;
#pragma unroll
        for (int i = ty; i < 32; i += 8) {
            int k = by * 32 + i, c = bx * 32 + tx;
            float v;
            if (c < 256) v = W1a[k * 256 + c];
            else if (c < 512) v = W1e[k * 256 + c - 256];
            else if (c < 768) v = R1a[k * 256 + c - 512];
            else v = R1e[k * 256 + c - 768];
            sh[i * 33 + tx] = v;
        }
        __syncthreads();
#pragma unroll
        for (int i = ty; i < 32; i += 8) {
            float x = sh[tx * 33 + i];
            __hip_bfloat16 bh = __float2bfloat16(x);
            float r = x - __bfloat162float(bh);
            __hip_bfloat16 bl = __float2bfloat16(r);
            WThi[(size_t)(bx * 32 + i) * 256 + by * 32 + tx] = *(unsigned short*)&bh;
            WTlo[(size_t)(bx * 32 + i) * 256 + by * 32 + tx] = *(unsigned short*)&bl;
        }
        return;
    }
    b -= 256;
    if (b < 8) {
        float* frow = sh;
        float* red = sh + 256;
        int t = *tptr;
        frow[tid] = feat[t * 256 + tid];
        __syncthreads();
        int j = b * 64 + (tid & 63);
        int ks = (tid >> 6) * 64;
        float s = 0.f;
#pragma unroll 16
        for (int k = ks; k < ks + 64; ++k) s = fmaf(frow[k], Wt[(size_t)k * 512 + j], s);
        red[tid] = s;
        __syncthreads();
        if (tid < 64) {
            float v = red[tid] + red[tid + 64] + red[tid + 128] + red[tid + 192] + bt[j];
            tf[j] = v >= 0.f ? v : 0.01f * v;
        }
        return;
    }
    b -= 8;
    if (b < 2500) {
        int idx = b * 256 + tid;
        int it = idx / (16 * NGR);
        int f = idx - it * (16 * NGR);
        u32 fk0, fk1, o0, o1;
        threefry(0u, 42u, 0u, (u32)it, fk0, fk1);
        threefry(fk0, fk1, 0u, (u32)f, o0, o1);
        u32 bits = o0 ^ o1;
        float fl = __uint_as_float((bits >> 9) | 0x3F800000u) - 1.0f;
        float u = fmaxf(TINYF, fl + TINYF);
        gum[idx] = -logf(-logf(u));
        return;
    }
    b -= 2500;
    if (b < 128) {
        int o = b * 256 + tid;
        int outi = o >> 3, sl = o & 7;
        int k = outi >> 3, q = outi & 7, sel = q >> 2, hh = q & 3;
        const float* av = (sel ? ar2a : al2a) + hh * 256 + sl * 32;
        const float* wr = W2a + (size_t)k * 1024 + hh * 256 + sl * 32;
        float s = 0.f;
#pragma unroll 8
        for (int d = 0; d < 32; ++d) s = fmaf(wr[d], av[d], s);
        sh[tid] = s;
        __syncthreads();
        if ((tid & 7) == 0) {
            float v = ((sh[tid] + sh[tid + 1]) + (sh[tid + 2] + sh[tid + 3])) +
                      ((sh[tid + 4] + sh[tid + 5]) + (sh[tid + 6] + sh[tid + 7]));
            wal[outi] = v;
        }
        return;
    }
    b -= 128;
    if (b < 235) {
        int idx = b * 256 + tid;
        if (idx < NGR * 6) zreg[idx] = 0.f;
        return;
    }
    b -= 235;
    {
        int c = b * 256 + tid;
        packb[c] = (c < 512) ? 0.f : ((c < 768) ? b1a[c - 512] : b1e[c - 768]);
    }
}

// ---------- bf16x3 MFMA GEMM (f32-emulation), XCD-swizzled, fused el/er epilogue ----------
__global__ __launch_bounds__(256) void gemm_bf16x3(
    const unsigned short* __restrict__ Ahi, const unsigned short* __restrict__ Alo,
    const unsigned short* __restrict__ Bhi, const unsigned short* __restrict__ Blo,
    float* __restrict__ C, const float* __restrict__ bias,
    const float* __restrict__ al1a, const float* __restrict__ ar1a,
    const float* __restrict__ al1e, const float* __restrict__ ar1e,
    float* __restrict__ el, float* __restrict__ er, int M)
{
    constexpr int K = 256;
    __shared__ unsigned short AsH[2][128 * 32];
    __shared__ unsigned short AsL[2][128 * 32];
    __shared__ unsigned short BsH[2][128 * 32];
    __shared__ unsigned short BsL[2][128 * 32];
    const int tid = threadIdx.x;
    const int lane = tid & 63;
    const int w = tid >> 6, wr = w >> 1, wc = w & 1;
    int lin = blockIdx.y * 8 + blockIdx.x;
    int wg = (lin & 7) * 79 + (lin >> 3);
    const int bm = (wg >> 3) * 128, bn = (wg & 7) * 128;
    const int fr = lane & 15, fq = lane >> 4;
    const int srow = tid >> 2;
    const int sbyte = (tid & 3) * 16;
    f32x4 acc[4][4] = {};

    auto stage = [&](int b, int k0) {
        const char* pA[2] = {(const char*)Ahi, (const char*)Alo};
        const char* pB[2] = {(const char*)Bhi, (const char*)Blo};
        char* dA[2] = {(char*)AsH[b], (char*)AsL[b]};
        char* dB[2] = {(char*)BsH[b], (char*)BsL[b]};
#pragma unroll
        for (int q = 0; q < 2; ++q) {
            const char* ga0 = pA[q] + ((size_t)(bm + srow) * K + k0) * 2 + sbyte;
            const char* ga1 = pA[q] + ((size_t)(bm + 64 + srow) * K + k0) * 2 + sbyte;
            const char* gb0 = pB[q] + ((size_t)(bn + srow) * K + k0) * 2 + sbyte;
            const char* gb1 = pB[q] + ((size_t)(bn + 64 + srow) * K + k0) * 2 + sbyte;
            __builtin_amdgcn_global_load_lds((const __attribute__((address_space(1))) void*)ga0,
                (__attribute__((address_space(3))) void*)(dA[q] + tid * 16), 16, 0, 0);
            __builtin_amdgcn_global_load_lds((const __attribute__((address_space(1))) void*)ga1,
                (__attribute__((address_space(3))) void*)(dA[q] + 4096 + tid * 16), 16, 0, 0);
            __builtin_amdgcn_global_load_lds((const __attribute__((address_space(1))) void*)gb0,
                (__attribute__((address_space(3))) void*)(dB[q] + tid * 16), 16, 0, 0);
            __builtin_amdgcn_global_load_lds((const __attribute__((address_space(1))) void*)gb1,
                (__attribute__((address_space(3))) void*)(dB[q] + 4096 + tid * 16), 16, 0, 0);
        }
    };

    stage(0, 0);
    __syncthreads();
    int buf = 0;
    for (int t = 0; t < 8; ++t) {
        if (t < 7) stage(buf ^ 1, (t + 1) * 32);
        const char* ah = (const char*)AsH[buf];
        const char* al = (const char*)AsL[buf];
        const char* bh = (const char*)BsH[buf];
        const char* bl = (const char*)BsL[buf];
        short8 afh[4], afl[4], bfh[4], bfl[4];
#pragma unroll
        for (int m = 0; m < 4; ++m) {
            int o = (wr * 64 + m * 16 + fr) * 64 + fq * 16;
            afh[m] = *(const short8*)(ah + o);
            afl[m] = *(const short8*)(al + o);
        }
#pragma unroll
        for (int n = 0; n < 4; ++n) {
            int o = (wc * 64 + n * 16 + fr) * 64 + fq * 16;
            bfh[n] = *(const short8*)(bh + o);
            bfl[n] = *(const short8*)(bl + o);
        }
#pragma unroll
        for (int m = 0; m < 4; ++m)
#pragma unroll
            for (int n = 0; n < 4; ++n) {
                acc[m][n] = __builtin_amdgcn_mfma_f32_16x16x32_bf16(afl[m], bfh[n], acc[m][n], 0, 0, 0);
                acc[m][n] = __builtin_amdgcn_mfma_f32_16x16x32_bf16(afh[m], bfl[n], acc[m][n], 0, 0, 0);
                acc[m][n] = __builtin_amdgcn_mfma_f32_16x16x32_bf16(afh[m], bfh[n], acc[m][n], 0, 0, 0);
            }
        __syncthreads();
        buf ^= 1;
    }
#pragma unroll
    for (int m = 0; m < 4; ++m) {
#pragma unroll
        for (int i = 0; i < 4; ++i) {
            int row = bm + wr * 64 + m * 16 + fq * 4 + i;
            if (row >= M) continue;
#pragma unroll
            for (int n = 0; n < 4; ++n) {
                int col = bn + wc * 64 + n * 16 + fr;
                C[(size_t)row * 1024 + col] = acc[m][n][i] + bias[col];
            }
        }
    }
    // ---- fused el/er epilogue: h-region col tiles only (bn < 512) ----
    // Wave (wr,wc) owns sub-head sub = bn/64 + wc entirely (64 cols = n*16+fr).
    if (bn < 512) {
        int sub = (bn >> 6) + wc;
        const float* alp = ((sub >= 4) ? al1e : al1a) + (sub & 3) * 64;
        const float* arp = ((sub >= 4) ? ar1e : ar1a) + (sub & 3) * 64;
        float av[4], rv[4];
#pragma unroll
        for (int n = 0; n < 4; ++n) { av[n] = alp[n * 16 + fr]; rv[n] = arp[n * 16 + fr]; }
#pragma unroll
        for (int m = 0; m < 4; ++m) {
#pragma unroll
            for (int i = 0; i < 4; ++i) {
                float pl = acc[m][0][i] * av[0];
                pl = fmaf(acc[m][1][i], av[1], pl);
                pl = fmaf(acc[m][2][i], av[2], pl);
                pl = fmaf(acc[m][3][i], av[3], pl);
                float pr = acc[m][0][i] * rv[0];
                pr = fmaf(acc[m][1][i], rv[1], pr);
                pr = fmaf(acc[m][2][i], rv[2], pr);
                pr = fmaf(acc[m][3][i], rv[3], pr);
#pragma unroll
                for (int o = 1; o < 16; o <<= 1) {
                    pl += __shfl_xor(pl, o, 64);
                    pr += __shfl_xor(pr, o, 64);
                }
                int row = bm + wr * 64 + m * 16 + fq * 4 + i;
                if (fr == 0 && row < M) {
                    el[row * 8 + sub] = pl;
                    er[row * 8 + sub] = pr;
                }
            }
        }
    }
}

// ---------- CSR edge softmax (L1) ----------
__global__ void k_softmax_csr(const float* __restrict__ el, const float* __restrict__ er,
                              const int* __restrict__ rowptr, const int* __restrict__ colidx,
                              const int* __restrict__ src,
                              float* __restrict__ ee, int H, int hshift, int total)
{
    int idx = blockIdx.x * blockDim.x + threadIdx.x;
    if (idx >= total) return;
    int n = idx >> hshift, hh = idx & (H - 1);
    float ern = er[n * H + hh];
    int i0 = rowptr[n], i1 = rowptr[n + 1];
    float mx = -INFINITY;
    for (int i = i0; i < i1; ++i) {
        float v = el[src[colidx[i]] * H + hh] + ern;
        v = v >= 0.f ? v : 0.2f * v;
        mx = fmaxf(mx, v);
    }
    float s = 0.f;
    for (int i = i0; i < i1; ++i) {
        int e = colidx[i];
        float v = el[src[e] * H + hh] + ern;
        v = v >= 0.f ? v : 0.2f * v;
        float ex = expf(v - mx);
        ee[(size_t)e * H + hh] = ex;
        s += ex;
    }
    for (int i = i0; i < i1; ++i) {
        int e = colidx[i];
        ee[(size_t)e * H + hh] /= s;
    }
}

// ---------- L1 aggregation -> raw accumulator (4-way load batching) ----------
__global__ void k_agg_acc(const float* __restrict__ alpha,
                          const int* __restrict__ rowptr, const int* __restrict__ colidx,
                          const int* __restrict__ src,
                          const float* __restrict__ regionA,
                          float* __restrict__ accb, int total)
{
    int idx = blockIdx.x * blockDim.x + threadIdx.x;
    if (idx >= total) return;
    int n = idx >> 7, c4 = idx & 127;
    int hh = c4 >> 4;
    const float4* h4 = (const float4*)regionA;
    float4 acc = h4[(size_t)n * 256 + 128 + c4];
    int i = rowptr[n], i1 = rowptr[n + 1];
    for (; i + 3 < i1; i += 4) {
        int e0 = colidx[i], e1 = colidx[i + 1], e2 = colidx[i + 2], e3 = colidx[i + 3];
        int s0 = src[e0], s1 = src[e1], s2 = src[e2], s3 = src[e3];
        float a0 = alpha[(size_t)e0 * 8 + hh];
        float a1 = alpha[(size_t)e1 * 8 + hh];
        float a2 = alpha[(size_t)e2 * 8 + hh];
        float a3 = alpha[(size_t)e3 * 8 + hh];
        float4 h0 = h4[(size_t)s0 * 256 + c4];
        float4 h1 = h4[(size_t)s1 * 256 + c4];
        float4 h2 = h4[(size_t)s2 * 256 + c4];
        float4 h3 = h4[(size_t)s3 * 256 + c4];
        acc.x = fmaf(a0, h0.x, acc.x); acc.y = fmaf(a0, h0.y, acc.y);
        acc.z = fmaf(a0, h0.z, acc.z); acc.w = fmaf(a0, h0.w, acc.w);
        acc.x = fmaf(a1, h1.x, acc.x); acc.y = fmaf(a1, h1.y, acc.y);
        acc.z = fmaf(a1, h1.z, acc.z); acc.w = fmaf(a1, h1.w, acc.w);
        acc.x = fmaf(a2, h2.x, acc.x); acc.y = fmaf(a2, h2.y, acc.y);
        acc.z = fmaf(a2, h2.z, acc.z); acc.w = fmaf(a2, h2.w, acc.w);
        acc.x = fmaf(a3, h3.x, acc.x); acc.y = fmaf(a3, h3.y, acc.y);
        acc.z = fmaf(a3, h3.z, acc.z); acc.w = fmaf(a3, h3.w, acc.w);
    }
    for (; i < i1; ++i) {
        int e0 = colidx[i];
        float a0 = alpha[(size_t)e0 * 8 + hh];
        float4 h0 = h4[(size_t)src[e0] * 256 + c4];
        acc.x = fmaf(a0, h0.x, acc.x); acc.y = fmaf(a0, h0.y, acc.y);
        acc.z = fmaf(a0, h0.z, acc.z); acc.w = fmaf(a0, h0.w, acc.w);
    }
    ((float4*)accb)[(size_t)n * 128 + c4] = acc;
}

// ---------- node-linear v2: reconstructs a2/e2 from acc+tf (bit-identical) ----------
__global__ __launch_bounds__(256) void k_node_linear(
    const float* __restrict__ accb, const float* __restrict__ tf,
    const float* __restrict__ We, const float* __restrict__ Re, const float* __restrict__ be,
    const float* __restrict__ wal,
    const float* __restrict__ al2e, const float* __restrict__ ar2e,
    float* __restrict__ h2e, float* __restrict__ e3,
    float* __restrict__ el2e, float* __restrict__ er2e,
    float* __restrict__ el2a, float* __restrict__ er2a)
{
    __shared__ float As[8 * 1024];
    __shared__ float red[2048];
    __shared__ float hl[8][16];
    int tid = threadIdx.x;
    int m0 = blockIdx.x * 8;
    for (int i = tid; i < 8 * 128; i += 256) {
        int row = i >> 7, c = (i & 127) << 2;
        float4 a = *(const float4*)(accb + (size_t)(m0 + row) * 512 + c);
        int cc = (c + 256) & 511;
        float4 ta = *(const float4*)(tf + c);
        float4 te = *(const float4*)(tf + cc);
        float4 xa, xe;
        xa.x = a.x + ta.x; xa.y = a.y + ta.y; xa.z = a.z + ta.z; xa.w = a.w + ta.w;
        xe.x = a.x + te.x; xe.y = a.y + te.y; xe.z = a.z + te.z; xe.w = a.w + te.w;
        xa.x = xa.x >= 0.f ? xa.x : 0.01f * xa.x;
        xa.y = xa.y >= 0.f ? xa.y : 0.01f * xa.y;
        xa.z = xa.z >= 0.f ? xa.z : 0.01f * xa.z;
        xa.w = xa.w >= 0.f ? xa.w : 0.01f * xa.w;
        xe.x = xe.x >= 0.f ? xe.x : 0.01f * xe.x;
        xe.y = xe.y >= 0.f ? xe.y : 0.01f * xe.y;
        xe.z = xe.z >= 0.f ? xe.z : 0.01f * xe.z;
        xe.w = xe.w >= 0.f ? xe.w : 0.01f * xe.w;
        *(float4*)(As + row * 1024 + c) = xa;
        *(float4*)(As + row * 1024 + 512 + cc) = xe;
    }
    __syncthreads();
    {
        int j = tid & 31, ks = tid >> 5;
        const float* B = (j < 16) ? We : Re;
        int jj = j & 15;
        float acc[8] = {};
        int k0 = ks * 64;
        for (int kk = 0; kk < 64; kk += 4) {
            int k = k0 + kk;
            float b0 = B[(k + 0) * 16 + jj];
            float b1 = B[(k + 1) * 16 + jj];
            float b2 = B[(k + 2) * 16 + jj];
            float b3 = B[(k + 3) * 16 + jj];
#pragma unroll
            for (int r = 0; r < 8; ++r) {
                float4 a = *(const float4*)(As + r * 1024 + 512 + k);
                acc[r] = fmaf(a.x, b0, acc[r]);
                acc[r] = fmaf(a.y, b1, acc[r]);
                acc[r] = fmaf(a.z, b2, acc[r]);
                acc[r] = fmaf(a.w, b3, acc[r]);
            }
        }
#pragma unroll
        for (int r = 0; r < 8; ++r) red[(r * 32 + j) * 8 + ks] = acc[r];
    }
    __syncthreads();
    {
        int r = tid >> 5, jo = tid & 31;
        const float* rp = red + (r * 32 + jo) * 8;
        float acc = ((rp[0] + rp[1]) + (rp[2] + rp[3])) + ((rp[4] + rp[5]) + (rp[6] + rp[7]));
        int m = m0 + r, jj = jo & 15;
        if (jo < 16) { h2e[(size_t)m * 16 + jj] = acc; hl[r][jj] = acc; }
        else         e3[(size_t)m * 16 + jj] = acc + be[jj];
    }
    __syncthreads();
    {
        int q = tid & 7, ks2 = tid >> 3;
        float acc[8] = {};
        int k0 = ks2 * 16;
        for (int kk = 0; kk < 16; ++kk) {
            int k = k0 + kk;
            float b = wal[k * 8 + q];
#pragma unroll
            for (int r = 0; r < 8; ++r)
                acc[r] = fmaf(As[r * 1024 + k], b, acc[r]);
        }
#pragma unroll
        for (int r = 0; r < 8; ++r) red[(r * 8 + q) * 32 + ks2] = acc[r];
    }
    __syncthreads();
    if (tid < 64) {
        const float* rp = red + tid * 32;
        float acc = 0.f;
#pragma unroll
        for (int g = 0; g < 32; ++g) acc += rp[g];
        int r = tid >> 3, q = tid & 7;
        int m = m0 + r;
        if (q < 4) el2a[m * 4 + q] = acc;
        else       er2a[m * 4 + (q - 4)] = acc;
    }
    if (tid >= 64 && tid < 72) {
        int rr = tid - 64;
        float sl = 0.f, sr = 0.f;
        const float* hp = hl[rr];
        for (int d = 0; d < 16; ++d) { float v = hp[d]; sl = fmaf(v, al2e[d], sl); sr = fmaf(v, ar2e[d], sr); }
        el2e[m0 + rr] = sl;
        er2e[m0 + rr] = sr;
    }
}

// ---------- fused L2 softmax: 2a+walpha (idx<N*4) | e-head agg (rest) ----------
__global__ void k_sm_l2(const float* __restrict__ el2a, const float* __restrict__ er2a,
                        const float* __restrict__ el2e, const float* __restrict__ er2e,
                        const int* __restrict__ rowptr, const int* __restrict__ colidx,
                        const int* __restrict__ src,
                        const float* __restrict__ h2e,
                        float* __restrict__ walpha, float* __restrict__ e3, int N)
{
    int idx = blockIdx.x * blockDim.x + threadIdx.x;
    if (idx < N * 4) {
        int n = idx >> 2, hh = idx & 3;
        float ern = er2a[n * 4 + hh];
        int i0 = rowptr[n], i1 = rowptr[n + 1];
        float mx = -INFINITY;
        for (int i = i0; i < i1; ++i) {
            float v = el2a[src[colidx[i]] * 4 + hh] + ern;
            v = v >= 0.f ? v : 0.2f * v;
            mx = fmaxf(mx, v);
        }
        float s = 0.f;
        for (int i = i0; i < i1; ++i) {
            float v = el2a[src[colidx[i]] * 4 + hh] + ern;
            v = v >= 0.f ? v : 0.2f * v;
            s += expf(v - mx);
        }
        for (int i = i0; i < i1; ++i) {
            int e = colidx[i];
            int sn = src[e];
            float v = el2a[sn * 4 + hh] + ern;
            v = v >= 0.f ? v : 0.2f * v;
            float alpha = expf(v - mx) / s;
            atomicAdd(&walpha[sn * 4 + hh], alpha);
        }
        return;
    }
    int n = idx - N * 4;
    if (n >= N) return;
    float ern = er2e[n];
    int i0 = rowptr[n], i1 = rowptr[n + 1];
    float mx = -INFINITY;
    for (int i = i0; i < i1; ++i) {
        float v = el2e[src[colidx[i]]] + ern;
        v = v >= 0.f ? v : 0.2f * v;
        mx = fmaxf(mx, v);
    }
    float s = 0.f;
    for (int i = i0; i < i1; ++i) {
        float v = el2e[src[colidx[i]]] + ern;
        v = v >= 0.f ? v : 0.2f * v;
        s += expf(v - mx);
    }
    float4* e34 = (float4*)(e3 + (size_t)n * 16);
    float4 a0 = e34[0], a1 = e34[1], a2 = e34[2], a3 = e34[3];
    for (int i = i0; i < i1; ++i) {
        int e = colidx[i];
        int sn = src[e];
        float v = el2e[sn] + ern;
        v = v >= 0.f ? v : 0.2f * v;
        float al = expf(v - mx) / s;
        const float4* hp = (const float4*)(h2e + (size_t)sn * 16);
        float4 h0 = hp[0], h1 = hp[1], h2 = hp[2], h3 = hp[3];
        a0.x = fmaf(al, h0.x, a0.x); a0.y = fmaf(al, h0.y, a0.y); a0.z = fmaf(al, h0.z, a0.z); a0.w = fmaf(al, h0.w, a0.w);
        a1.x = fmaf(al, h1.x, a1.x); a1.y = fmaf(al, h1.y, a1.y); a1.z = fmaf(al, h1.z, a1.z); a1.w = fmaf(al, h1.w, a1.w);
        a2.x = fmaf(al, h2.x, a2.x); a2.y = fmaf(al, h2.y, a2.y); a2.z = fmaf(al, h2.z, a2.z); a2.w = fmaf(al, h2.w, a2.w);
        a3.x = fmaf(al, h3.x, a3.x); a3.y = fmaf(al, h3.y, a3.y); a3.z = fmaf(al, h3.z, a3.z); a3.w = fmaf(al, h3.w, a3.w);
    }
    e34[0] = a0; e34[1] = a1; e34[2] = a2; e34[3] = a3;
}

// ---------- attr partials (reconstructs a2 from acc+tf) ----------
__global__ __launch_bounds__(256) void k_pwa(const float* __restrict__ accb,
                                             const float* __restrict__ tf,
                                             const float* __restrict__ walpha,
                                             float* __restrict__ pwa)
{
    int b = blockIdx.x, t = threadIdx.x;
    float tf0 = tf[t], tf1 = tf[t + 256];
    float acc[5][2] = {};
    int n0 = b * 80, n1 = min(n0 + 80, NGR);
    for (int n = n0; n < n1; ++n) {
        const float* row = accb + (size_t)n * 512;
        const float* wa = walpha + n * 4;
        float w0 = wa[0], w1 = wa[1], w2 = wa[2], w3 = wa[3];
        float x0 = row[t] + tf0;       x0 = x0 >= 0.f ? x0 : 0.01f * x0;
        float x1 = row[t + 256] + tf1; x1 = x1 >= 0.f ? x1 : 0.01f * x1;
        acc[0][0] = fmaf(w0, x0, acc[0][0]); acc[0][1] = fmaf(w0, x1, acc[0][1]);
        acc[1][0] = fmaf(w1, x0, acc[1][0]); acc[1][1] = fmaf(w1, x1, acc[1][1]);
        acc[2][0] = fmaf(w2, x0, acc[2][0]); acc[2][1] = fmaf(w2, x1, acc[2][1]);
        acc[3][0] = fmaf(w3, x0, acc[3][0]); acc[3][1] = fmaf(w3, x1, acc[3][1]);
        acc[4][0] += x0; acc[4][1] += x1;
    }
#pragma unroll
    for (int q = 0; q < 5; ++q) {
        pwa[(size_t)b * 2560 + q * 512 + t] = acc[q][0];
        pwa[(size_t)b * 2560 + q * 512 + t + 256] = acc[q][1];
    }
}
__global__ void k_pwa_fin(const float* __restrict__ pwa, float* __restrict__ waw)
{
    int idx = blockIdx.x * blockDim.x + threadIdx.x;
    if (idx >= 2560) return;
    float s = 0.f;
    for (int b = 0; b < 125; ++b) s += pwa[(size_t)b * 2560 + idx];
    waw[idx] = s;
}

// ---------- attr GEMV (64 blocks) ----------
__global__ __launch_bounds__(256) void k_gemv3(const float* __restrict__ waw,
                                               const float* __restrict__ W2a, const float* __restrict__ R2a,
                                               const float* __restrict__ b2a,
                                               float* __restrict__ attrL)
{
    __shared__ float red[256];
    int b = blockIdx.x, t = threadIdx.x;
    int c = b * 16 + (t & 15);
    int hh = (b * 16) >> 8;
    int ks = (t >> 4) * 32;
    const float* wh = waw + hh * 512;
    const float* w4 = waw + 4 * 512;
    float s = 0.f;
#pragma unroll 8
    for (int k = ks; k < ks + 32; ++k) {
        s = fmaf(wh[k], W2a[(size_t)k * 1024 + c], s);
        s = fmaf(w4[k], R2a[(size_t)k * 1024 + c], s);
    }
    red[t] = s;
    __syncthreads();
    if (t < 16) {
        float v = 0.f;
#pragma unroll
        for (int g = 0; g < 16; ++g) v += red[t + g * 16];
        v = v / (float)NGR + b2a[b * 16 + t];
        attrL[b * 16 + t] = v >= 0.f ? v : 0.01f * v;
    }
}

// ---------- node_attr ----------
__global__ __launch_bounds__(256) void k_nattr2(const float* __restrict__ attrL,
                                                const float* __restrict__ Wo, const float* __restrict__ bo,
                                                float* __restrict__ out)
{
    __shared__ float al[64];
    int i = blockIdx.x, t = threadIdx.x;
    if (t < 64) al[t] = attrL[i * 64 + t];
    __syncthreads();
    float acc = 0.f;
#pragma unroll 8
    for (int d = 0; d < 64; ++d) acc = fmaf(al[d], Wo[d * 256 + t], acc);
    acc += bo[t];
    out[i * 256 + t] = acc;
    out[4096 + i * 256 + t] = acc;
}

// ---------- sampler stage 1: chunked softmax stats ----------
__global__ __launch_bounds__(256) void k_e3stats(const float* __restrict__ e3,
                                                 float* __restrict__ pm, float* __restrict__ ps)
{
    __shared__ float lds[4000];
    __shared__ float redm[16][16];
    __shared__ float reds[16][16];
    __shared__ float cm[16];
    int b = blockIdx.x, tid = threadIdx.x;
    int base = b * 250 * 16;
    for (int i = tid; i < 4000; i += 256) lds[i] = e3[base + i];
    __syncthreads();
    int c = tid & 15, g = tid >> 4;
    float mx = -INFINITY;
    for (int q = g; q < 250; q += 16) mx = fmaxf(mx, lds[q * 16 + c]);
    redm[c][g] = mx;
    __syncthreads();
    if (tid < 16) {
        float m = redm[tid][0];
        for (int q = 1; q < 16; ++q) m = fmaxf(m, redm[tid][q]);
        cm[tid] = m;
    }
    __syncthreads();
    float mb = cm[c];
    float s = 0.f;
    for (int q = g; q < 250; q += 16) s += expf(lds[q * 16 + c] - mb);
    reds[c][g] = s;
    __syncthreads();
    if (tid < 16) {
        float ss = 0.f;
        for (int q = 0; q < 16; ++q) ss += reds[tid][q];
        pm[b * 16 + tid] = cm[tid];
        ps[b * 16 + tid] = ss;
    }
}

// ---------- sampler stage 2: top-5 of g + p per (it,r,chunk) ----------
__global__ __launch_bounds__(256) void k_top5(const float* __restrict__ e3, const float* __restrict__ gum,
                                              const float* __restrict__ pm, const float* __restrict__ ps,
                                              float* __restrict__ probs,
                                              float* __restrict__ t5v, int* __restrict__ t5i)
{
    __shared__ float wv[4];
    __shared__ int wi[4];
    int chunk = blockIdx.x, y = blockIdx.y;
    int it = y >> 4, r = y & 15;
    int tid = threadIdx.x, lane = tid & 63, wid = tid >> 6;
    float M = -INFINITY;
    for (int b = 0; b < 40; ++b) M = fmaxf(M, pm[b * 16 + r]);
    float S = 0.f;
    for (int b = 0; b < 40; ++b) S += ps[b * 16 + r] * expf(pm[b * 16 + r] - M);
    float mxr = M, ssr = S;
    const float* g = gum + (size_t)y * NGR;
    int jb = chunk * 1250;
    float sv[5]; int si[5];
#pragma unroll
    for (int q = 0; q < 5; ++q) {
        int o = q * 256 + tid;
        float s = -INFINITY; int idx = 0x7FFFFFFF;
        if (o < 1250) {
            int j = jb + o;
            float p = expf(e3[(size_t)j * 16 + r] - mxr) / ssr;
            if (it == 0) probs[(size_t)r * NGR + j] = p;
            s = g[j] + p;
            idx = j;
        }
        sv[q] = s; si[q] = idx;
    }
    int outb = (y * 8 + chunk) * 5;
    for (int round = 0; round < 5; ++round) {
        float best = sv[0]; int bi = si[0];
#pragma unroll
        for (int q = 1; q < 5; ++q)
            if (sv[q] > best || (sv[q] == best && si[q] < bi)) { best = sv[q]; bi = si[q]; }
#pragma unroll
        for (int o = 32; o > 0; o >>= 1) {
            float ov = __shfl_xor(best, o, 64); int oi = __shfl_xor(bi, o, 64);
            if (ov > best || (ov == best && oi < bi)) { best = ov; bi = oi; }
        }
        if (lane == 0) { wv[wid] = best; wi[wid] = bi; }
        __syncthreads();
        float gbv = wv[0]; int gbi = wi[0];
#pragma unroll
        for (int w2 = 1; w2 < 4; ++w2) {
            float ov = wv[w2]; int oi = wi[w2];
            if (ov > gbv || (ov == gbv && oi < gbi)) { gbv = ov; gbi = oi; }
        }
        if (tid == 0) { t5v[outb + round] = gbv; t5i[outb + round] = gbi; }
#pragma unroll
        for (int q = 0; q < 5; ++q) if (si[q] == gbi) { sv[q] = -INFINITY; si[q] = 0x7FFFFFFF; }
        __syncthreads();
    }
}

// ---------- sampler stage 3: sequential exclusion ----------
__global__ void k_select(const int* __restrict__ tptr, const float* __restrict__ t5v,
                         const int* __restrict__ t5i, float* __restrict__ out_edges)
{
    int r = threadIdx.x;
    if (r >= 16) return;
    int s0 = *tptr, s1 = -1, s2 = -1, s3 = -1;
    out_edges[r * 5] = (float)s0;
    for (int it = 0; it < 4; ++it) {
        float best = -INFINITY; int bi = 0x7FFFFFFF;
        int base = (it * 16 + r) * 40;
        for (int c = 0; c < 40; ++c) {
            int idx = t5i[base + c];
            if (idx == s0 || idx == s1 || idx == s2 || idx == s3) continue;
            float v = t5v[base + c];
            if (v > best || (v == best && idx < bi)) { best = v; bi = idx; }
        }
        if (it == 0) s1 = bi; else if (it == 1) s2 = bi; else if (it == 2) s3 = bi;
        out_edges[r * 5 + it + 1] = (float)bi;
    }
}

extern "C" void kernel_launch(void* const* d_in, const int* in_sizes, int n_in,
                              void* d_out, int out_size, void* d_ws, size_t ws_size,
                              hipStream_t stream)
{
    const float* feat = (const float*)d_in[0];
    const int* src = (const int*)d_in[1];
    const int* dst = (const int*)d_in[2];
    const int* tptr = (const int*)d_in[3];
    const float* W1a = (const float*)d_in[4];  const float* al1a = (const float*)d_in[5];
    const float* ar1a = (const float*)d_in[6]; const float* R1a = (const float*)d_in[7];
    const float* b1a = (const float*)d_in[8];
    const float* W1e = (const float*)d_in[9];  const float* al1e = (const float*)d_in[10];
    const float* ar1e = (const float*)d_in[11]; const float* R1e = (const float*)d_in[12];
    const float* b1e = (const float*)d_in[13];
    const float* W2a = (const float*)d_in[14]; const float* al2a = (const float*)d_in[15];
    const float* ar2a = (const float*)d_in[16]; const float* R2a = (const float*)d_in[17];
    const float* b2a = (const float*)d_in[18];
    const float* W2e = (const float*)d_in[19]; const float* al2e = (const float*)d_in[20];
    const float* ar2e = (const float*)d_in[21]; const float* R2e = (const float*)d_in[22];
    const float* b2e = (const float*)d_in[23];
    const float* Wt = (const float*)d_in[24];  const float* bt = (const float*)d_in[25];
    const float* Wo = (const float*)d_in[26];  const float* bo = (const float*)d_in[27];
    const int E = in_sizes[1];
    const int N = NGR;

    float* ws = (float*)d_ws;
    float* regionA = ws;
    size_t off = (size_t)N * 1024;
    auto alloc = [&](size_t n) { float* p = ws + off; off += (n + 3) & ~(size_t)3; return p; };
    float* accb = alloc((size_t)N * 512);
    float* tf   = alloc(512);
    float* el1  = alloc((size_t)N * 8);
    float* er1  = alloc((size_t)N * 8);
    float* el2a = alloc((size_t)N * 4);
    float* er2a = alloc((size_t)N * 4);
    float* el2e = alloc(N);
    float* er2e = alloc(N);
    float* h2e  = alloc((size_t)N * 16);
    float* e3   = alloc((size_t)N * 16);
    float* ee1  = alloc((size_t)E * 8);
    float* packb = alloc(1024);
    float* gum   = alloc((size_t)4 * 16 * NGR);
    float* wal   = alloc(512 * 8);
    float* pwa   = alloc(125 * 2560);
    float* waw   = alloc(2560);
    float* attrL = alloc(1024);
    float* pm    = alloc(40 * 16);
    float* ps    = alloc(40 * 16);
    float* t5v   = alloc(64 * 40);
    int*   t5i   = (int*)alloc(64 * 40);
    unsigned short* feathi = (unsigned short*)alloc((size_t)10112 * 128);
    unsigned short* featlo = (unsigned short*)alloc((size_t)10112 * 128);
    unsigned short* WThi = (unsigned short*)alloc((size_t)1024 * 128);
    unsigned short* WTlo = (unsigned short*)alloc((size_t)1024 * 128);
    float* zstart = alloc((size_t)N * 6);
    float* walpha = zstart;
    int* deg    = (int*)(zstart + (size_t)N * 4);
    int* cursor = deg + N;
    int* rowptr = (int*)alloc(N + 1);
    int* colidx = (int*)alloc(E);

    float* out = (float*)d_out;
    float* out_edges = out + 8192;
    float* out_probs = out + 8272;

    dim3 blk(256);

    k_prep<<<5631, blk, 0, stream>>>(feat, tptr, Wt, bt, W1a, W1e, R1a, R1e, b1a, b1e,
                                     W2a, al2a, ar2a, feathi, featlo, WThi, WTlo,
                                     tf, gum, wal, packb, zstart);
    k_deg<<<(E + 255) / 256, blk, 0, stream>>>(dst, deg, E);
    k_scan<<<1, blk, 0, stream>>>(deg, rowptr, N);
    k_scatter<<<(E + 255) / 256, blk, 0, stream>>>(dst, rowptr, cursor, colidx, E);

    gemm_bf16x3<<<dim3(8, 79), blk, 0, stream>>>(feathi, featlo, WThi, WTlo, regionA, packb,
                                                 al1a, ar1a, al1e, ar1e, el1, er1, N);
    k_softmax_csr<<<(N * 8 + 255) / 256, blk, 0, stream>>>(el1, er1, rowptr, colidx, src, ee1, 8, 3, N * 8);
    k_agg_acc<<<(N * 128 + 255) / 256, blk, 0, stream>>>(ee1, rowptr, colidx, src,
                                                         regionA, accb, N * 128);

    k_node_linear<<<N / 8, blk, 0, stream>>>(accb, tf, W2e, R2e, b2e, wal, al2e, ar2e,
                                             h2e, e3, el2e, er2e, el2a, er2a);
    k_sm_l2<<<(N * 5 + 255) / 256, blk, 0, stream>>>(el2a, er2a, el2e, er2e,
                                                     rowptr, colidx, src, h2e, walpha, e3, N);

    k_pwa<<<125, blk, 0, stream>>>(accb, tf, walpha, pwa);
    k_pwa_fin<<<10, blk, 0, stream>>>(pwa, waw);
    k_gemv3<<<64, blk, 0, stream>>>(waw, W2a, R2a, b2a, attrL);
    k_nattr2<<<16, blk, 0, stream>>>(attrL, Wo, bo, out);

    k_e3stats<<<40, blk, 0, stream>>>(e3, pm, ps);
    k_top5<<<dim3(8, 64), blk, 0, stream>>>(e3, gum, pm, ps, out_probs, t5v, t5i);
    k_select<<<1, 64, 0, stream>>>(tptr, t5v, t5i, out_edges);
}